// Round 1
// baseline (867.094 us; speedup 1.0000x reference)
//
#include <hip/hip_runtime.h>

#define B_ 256
#define C_ 248
#define P_ 50
#define T_ 4
#define H_ 8
#define D_ 31
#define DH_ 124
#define PT_ 200
#define O3_ 744

__device__ __forceinline__ float bf2f(unsigned short u) {
  union { unsigned int i; float f; } v; v.i = ((unsigned int)u) << 16; return v.f;
}
__device__ __forceinline__ unsigned short f2bf(float f) {
  union { float f; unsigned int i; } v; v.f = f;
  unsigned int r = v.i + 0x7fffu + ((v.i >> 16) & 1u);
  return (unsigned short)(r >> 16);
}

// K0: rel_emb fp32 -> bf16
__global__ void relcvt_kernel(const float* __restrict__ rel, unsigned short* __restrict__ out) {
  int i = blockIdx.x * 256 + threadIdx.x;
  if (i < 99 * DH_) out[i] = f2bf(rel[i]);
}

// K1: qkv projection GEMM. out tile 128 o x 64 s, fp32 LDS tiles, bf16 stores
__global__ __launch_bounds__(256) void qkv_kernel(
    const float* __restrict__ x, const float* __restrict__ w,
    const float* __restrict__ bias,
    unsigned short* __restrict__ q_ws, unsigned short* __restrict__ k_ws,
    unsigned short* __restrict__ v_ws) {
  __shared__ float xs[16][72];
  __shared__ float wts[16][136];
  const int tid = threadIdx.x;
  const int tx = tid & 15, ty = tid >> 4;
  const int s0 = blockIdx.x * 64;
  const int o0 = blockIdx.y * 128;
  float acc[8][4];
#pragma unroll
  for (int i = 0; i < 8; ++i) { acc[i][0]=0.f; acc[i][1]=0.f; acc[i][2]=0.f; acc[i][3]=0.f; }

  const int ls_k = ty;            // 0..15 (c row within chunk)
  const int ls_s = tx * 4;        // col
  const int s_l = s0 + ls_s;
  const int b_l = s_l / PT_;
  const int pt_l = s_l - b_l * PT_;
  const float* xbase = x + (size_t)b_l * C_ * PT_ + pt_l;

  const int wo = tid >> 2;        // 0..63
  const int wc = (tid & 3) << 2;  // 0,4,8,12

  for (int kc = 0; kc < 256; kc += 16) {
    int cx = kc + ls_k;
    float4 xv = make_float4(0.f,0.f,0.f,0.f);
    if (cx < C_) xv = *(const float4*)(xbase + (size_t)cx * PT_);
    float4 wv0 = make_float4(0.f,0.f,0.f,0.f);
    float4 wv1 = make_float4(0.f,0.f,0.f,0.f);
    int o_a = o0 + wo, o_b = o0 + 64 + wo;
    int cw = kc + wc;
    if (cw + 4 <= C_) {
      if (o_a < O3_) wv0 = *(const float4*)(w + (size_t)o_a * C_ + cw);
      if (o_b < O3_) wv1 = *(const float4*)(w + (size_t)o_b * C_ + cw);
    }
    __syncthreads();
    *(float4*)&xs[ls_k][ls_s] = xv;
    wts[wc+0][wo] = wv0.x; wts[wc+1][wo] = wv0.y; wts[wc+2][wo] = wv0.z; wts[wc+3][wo] = wv0.w;
    wts[wc+0][64+wo] = wv1.x; wts[wc+1][64+wo] = wv1.y; wts[wc+2][64+wo] = wv1.z; wts[wc+3][64+wo] = wv1.w;
    __syncthreads();
#pragma unroll
    for (int k = 0; k < 16; ++k) {
      float4 xv4 = *(const float4*)&xs[k][tx*4];
      float4 alo = *(const float4*)&wts[k][ty*8];
      float4 ahi = *(const float4*)&wts[k][ty*8+4];
      float a[8] = {alo.x,alo.y,alo.z,alo.w,ahi.x,ahi.y,ahi.z,ahi.w};
      float bx[4] = {xv4.x,xv4.y,xv4.z,xv4.w};
#pragma unroll
      for (int i = 0; i < 8; ++i)
#pragma unroll
        for (int j = 0; j < 4; ++j)
          acc[i][j] += a[i] * bx[j];
    }
  }
  const int sbase = s0 + tx*4;
  const int bb = sbase / PT_;
  const int pt = sbase - bb * PT_;
  const int p = pt >> 2;
#pragma unroll
  for (int i = 0; i < 8; ++i) {
    int o = o0 + ty*8 + i;
    if (o < O3_) {
      float bo = bias[o];
      int wi = o / C_;
      int r = o - wi * C_;
      int h = r / D_;
      int d = r - h * D_;
      unsigned short* dst = (wi == 0) ? q_ws : (wi == 1) ? k_ws : v_ws;
      size_t base = ((((size_t)bb * H_ + h) * P_ + p) * DH_) + (size_t)d * T_;
      ushort4 pk;
      pk.x = f2bf(acc[i][0] + bo);
      pk.y = f2bf(acc[i][1] + bo);
      pk.z = f2bf(acc[i][2] + bo);
      pk.w = f2bf(acc[i][3] + bo);
      *(ushort4*)(dst + base) = pk;
    }
  }
}

// K2: per-(b,h) attention: brel + dots + softmax + PV + residual -> pre1
__global__ __launch_bounds__(256) void attn_kernel(
    const unsigned short* __restrict__ q_ws, const unsigned short* __restrict__ k_ws,
    const unsigned short* __restrict__ v_ws, const unsigned short* __restrict__ rel_bf,
    const float* __restrict__ x, float* __restrict__ pre1) {
  __shared__ unsigned short qs[P_][DH_];
  __shared__ unsigned short ks[P_][DH_];
  __shared__ unsigned short vs[P_][DH_];
  __shared__ unsigned short brs[P_][100];
  __shared__ float sc[P_][52];
  const int tid = threadIdx.x;
  const int bh = blockIdx.x;
  const int b = bh >> 3, h = bh & 7;
  const size_t off = (size_t)bh * (P_ * DH_);
  const ushort4* qsrc = (const ushort4*)(q_ws + off);
  const ushort4* ksrc = (const ushort4*)(k_ws + off);
  const ushort4* vsrc = (const ushort4*)(v_ws + off);
  ushort4* qd = (ushort4*)&qs[0][0];
  ushort4* kd = (ushort4*)&ks[0][0];
  ushort4* vd = (ushort4*)&vs[0][0];
  for (int i = tid; i < (P_*DH_)/4; i += 256) {
    qd[i] = qsrc[i]; kd[i] = ksrc[i]; vd[i] = vsrc[i];
  }
  __syncthreads();
  // phase A: brs[p][r] = dot(q[p], rel[r]), tiled 2p x 4r
  for (int u = tid; u < 625; u += 256) {
    int p0 = (u / 25) * 2;
    int r0 = (u % 25) * 4;
    float acc[2][4] = {{0,0,0,0},{0,0,0,0}};
    for (int dh = 0; dh < DH_; dh += 4) {
      float qa[2][4];
#pragma unroll
      for (int i = 0; i < 2; ++i) {
        ushort4 t4 = *(const ushort4*)&qs[p0+i][dh];
        qa[i][0]=bf2f(t4.x); qa[i][1]=bf2f(t4.y); qa[i][2]=bf2f(t4.z); qa[i][3]=bf2f(t4.w);
      }
#pragma unroll
      for (int jr = 0; jr < 4; ++jr) {
        int r = r0 + jr;
        if (r < 99) {
          ushort4 t4 = *(const ushort4*)(rel_bf + r*DH_ + dh);
          float r0f=bf2f(t4.x), r1f=bf2f(t4.y), r2f=bf2f(t4.z), r3f=bf2f(t4.w);
          acc[0][jr] += qa[0][0]*r0f + qa[0][1]*r1f + qa[0][2]*r2f + qa[0][3]*r3f;
          acc[1][jr] += qa[1][0]*r0f + qa[1][1]*r1f + qa[1][2]*r2f + qa[1][3]*r3f;
        }
      }
    }
#pragma unroll
    for (int i = 0; i < 2; ++i)
#pragma unroll
      for (int jr = 0; jr < 4; ++jr) {
        int r = r0 + jr;
        if (r < 99) brs[p0+i][r] = f2bf(acc[i][jr]);
      }
  }
  __syncthreads();
  // phase B: sc[p][j] = (dot(q[p],k[j]) + brs[p][49+j-p]) * 31^-0.5
  const float scale = 0.17960530202677491f;
  for (int u = tid; u < 325; u += 256) {
    int p0 = (u / 13) * 2;
    int j0 = (u % 13) * 4;
    float acc[2][4] = {{0,0,0,0},{0,0,0,0}};
    for (int dh = 0; dh < DH_; dh += 4) {
      float qa[2][4];
#pragma unroll
      for (int i = 0; i < 2; ++i) {
        ushort4 t4 = *(const ushort4*)&qs[p0+i][dh];
        qa[i][0]=bf2f(t4.x); qa[i][1]=bf2f(t4.y); qa[i][2]=bf2f(t4.z); qa[i][3]=bf2f(t4.w);
      }
#pragma unroll
      for (int jj = 0; jj < 4; ++jj) {
        int j = j0 + jj;
        if (j < 50) {
          ushort4 t4 = *(const ushort4*)&ks[j][dh];
          float k0=bf2f(t4.x), k1=bf2f(t4.y), k2=bf2f(t4.z), k3=bf2f(t4.w);
          acc[0][jj] += qa[0][0]*k0 + qa[0][1]*k1 + qa[0][2]*k2 + qa[0][3]*k3;
          acc[1][jj] += qa[1][0]*k0 + qa[1][1]*k1 + qa[1][2]*k2 + qa[1][3]*k3;
        }
      }
    }
#pragma unroll
    for (int i = 0; i < 2; ++i)
#pragma unroll
      for (int jj = 0; jj < 4; ++jj) {
        int j = j0 + jj;
        if (j < 50) {
          int r = 49 + j - (p0 + i);
          sc[p0+i][j] = (acc[i][jj] + bf2f(brs[p0+i][r])) * scale;
        }
      }
  }
  __syncthreads();
  // phase C: row softmax, 4 lanes per row
  if (tid < 200) {
    int p = tid >> 2, l = tid & 3;
    float m = -1e30f;
    for (int j = l; j < P_; j += 4) m = fmaxf(m, sc[p][j]);
    m = fmaxf(m, __shfl_xor(m, 1));
    m = fmaxf(m, __shfl_xor(m, 2));
    float s = 0.f;
    for (int j = l; j < P_; j += 4) { float e = __expf(sc[p][j] - m); sc[p][j] = e; s += e; }
    s += __shfl_xor(s, 1);
    s += __shfl_xor(s, 2);
    float inv = 1.f / s;
    for (int j = l; j < P_; j += 4) sc[p][j] *= inv;
  }
  __syncthreads();
  // phase D: out = attn @ v, + x residual -> pre1
  for (int u = tid; u < P_ * D_; u += 256) {
    int p = u / D_, d = u - (u / D_) * D_;
    float a0=0.f,a1=0.f,a2=0.f,a3=0.f;
    for (int j = 0; j < P_; ++j) {
      float at = sc[p][j];
      ushort4 v4 = *(const ushort4*)&vs[j][d*4];
      a0 += at * bf2f(v4.x);
      a1 += at * bf2f(v4.y);
      a2 += at * bf2f(v4.z);
      a3 += at * bf2f(v4.w);
    }
    int c = h * D_ + d;
    size_t idx = (((size_t)b * C_ + c) * P_ + p) * T_;
    float4 xr = *(const float4*)(x + idx);
    float4 o = make_float4(a0 + xr.x, a1 + xr.y, a2 + xr.z, a3 + xr.w);
    *(float4*)(pre1 + idx) = o;
  }
}

// BN batch-stat reduction: per channel over (B, PT). 256 threads = one b each.
__global__ __launch_bounds__(256) void bnstat_kernel(
    const float* __restrict__ t, const float* __restrict__ g, const float* __restrict__ be,
    float* __restrict__ a, float* __restrict__ bs, int nch) {
  const int c = blockIdx.x;
  const int tid = threadIdx.x;
  const float* base = t + ((size_t)tid * nch + c) * PT_;
  float s = 0.f, s2 = 0.f;
  for (int i = 0; i < PT_; i += 4) {
    float4 v = *(const float4*)(base + i);
    s += v.x + v.y + v.z + v.w;
    s2 += v.x*v.x + v.y*v.y + v.z*v.z + v.w*v.w;
  }
#pragma unroll
  for (int off = 32; off > 0; off >>= 1) {
    s += __shfl_down(s, off);
    s2 += __shfl_down(s2, off);
  }
  __shared__ float r1[4], r2[4];
  if ((tid & 63) == 0) { r1[tid>>6] = s; r2[tid>>6] = s2; }
  __syncthreads();
  if (tid == 0) {
    s = r1[0]+r1[1]+r1[2]+r1[3];
    s2 = r2[0]+r2[1]+r2[2]+r2[3];
    const float inv = 1.f / (float)(B_ * PT_);
    float m = s * inv;
    float var = s2 * inv - m * m;
    float ai = g[c] * rsqrtf(var + 1e-5f);
    a[c] = ai;
    bs[c] = be[c] - m * ai;
  }
}

// K4: conv1(1x3) + conv2(1x5) over BN1(pre1), one block per b
__global__ __launch_bounds__(256) void cfe12_kernel(
    const float* __restrict__ pre1, const float* __restrict__ a1, const float* __restrict__ b1,
    const float* __restrict__ w1, const float* __restrict__ bc1,
    const float* __restrict__ w2, const float* __restrict__ bc2,
    float* __restrict__ y16) {
  const int b = blockIdx.x;
  const int tid = threadIdx.x;
  __shared__ unsigned short xs[62][PT_];
  __shared__ unsigned short w1s[8*C_*3];
  __shared__ unsigned short w2s[8*C_*5];
  for (int i = tid; i < 8*C_*3; i += 256) w1s[i] = f2bf(w1[i]);
  for (int i = tid; i < 8*C_*5; i += 256) w2s[i] = f2bf(w2[i]);
  float acc[4][4];
#pragma unroll
  for (int l = 0; l < 4; ++l) { acc[l][0]=0.f; acc[l][1]=0.f; acc[l][2]=0.f; acc[l][3]=0.f; }
  for (int cc = 0; cc < C_; cc += 62) {
    __syncthreads();
    for (int e = tid; e < 62*PT_; e += 256) {
      int cl = e / PT_, pt = e - cl * PT_;
      int c = cc + cl;
      float v = pre1[((size_t)b * C_ + c) * PT_ + pt];
      xs[cl][pt] = f2bf(v * a1[c] + b1[c]);
    }
    __syncthreads();
    for (int l = 0; l < 4; ++l) {
      int u = tid + l * 256;
      if (u >= 800) break;
      int f = u / P_, p = u - (u / P_) * P_;
      if (f < 8) {
        const unsigned short* wp = w1s + (f * C_ + cc) * 3;
        for (int cl = 0; cl < 62; ++cl) {
          ushort4 x4 = *(const ushort4*)&xs[cl][p*4];
          float x0=bf2f(x4.x), x1=bf2f(x4.y), x2=bf2f(x4.z), x3=bf2f(x4.w);
          float w0=bf2f(wp[cl*3]), w1v=bf2f(wp[cl*3+1]), w2v=bf2f(wp[cl*3+2]);
          acc[l][0] += x0*w1v + x1*w2v;
          acc[l][1] += x0*w0 + x1*w1v + x2*w2v;
          acc[l][2] += x1*w0 + x2*w1v + x3*w2v;
          acc[l][3] += x2*w0 + x3*w1v;
        }
      } else {
        const unsigned short* wp = w2s + ((f-8) * C_ + cc) * 5;
        for (int cl = 0; cl < 62; ++cl) {
          ushort4 x4 = *(const ushort4*)&xs[cl][p*4];
          float x0=bf2f(x4.x), x1=bf2f(x4.y), x2=bf2f(x4.z), x3=bf2f(x4.w);
          float w0=bf2f(wp[cl*5]), w1v=bf2f(wp[cl*5+1]), w2v=bf2f(wp[cl*5+2]);
          float w3v=bf2f(wp[cl*5+3]), w4v=bf2f(wp[cl*5+4]);
          acc[l][0] += x0*w2v + x1*w3v + x2*w4v;
          acc[l][1] += x0*w1v + x1*w2v + x2*w3v + x3*w4v;
          acc[l][2] += x0*w0 + x1*w1v + x2*w2v + x3*w3v;
          acc[l][3] += x1*w0 + x2*w1v + x3*w2v;
        }
      }
    }
  }
  for (int l = 0; l < 4; ++l) {
    int u = tid + l * 256;
    if (u >= 800) break;
    int f = u / P_, p = u - (u / P_) * P_;
    float bias = (f < 8) ? bc1[f] : bc2[f-8];
    float4 o = make_float4(acc[l][0]+bias, acc[l][1]+bias, acc[l][2]+bias, acc[l][3]+bias);
    *(float4*)(y16 + ((size_t)b * 16 + f) * PT_ + p*4) = o;
  }
}

// K6: ELU(BN_cfe(y16)) -> conv3 (16->248) + BN1-residual -> pre2
__global__ __launch_bounds__(256) void cfe3_kernel(
    const float* __restrict__ y16, const float* __restrict__ ac, const float* __restrict__ bcf,
    const float* __restrict__ w3, const float* __restrict__ bc3,
    const float* __restrict__ pre1, const float* __restrict__ a1, const float* __restrict__ b1,
    float* __restrict__ pre2) {
  const int b = blockIdx.x;
  const int tid = threadIdx.x;
  __shared__ float zs[16][PT_];
  __shared__ float w3s[C_][16];
  for (int i = tid; i < C_*16; i += 256) w3s[i >> 4][i & 15] = w3[i];
  for (int e = tid; e < 16*PT_; e += 256) {
    int f = e / PT_, pt = e - f * PT_;
    float v = y16[((size_t)b*16 + f) * PT_ + pt] * ac[f] + bcf[f];
    zs[f][pt] = (v > 0.f) ? v : (__expf(v) - 1.f);
  }
  __syncthreads();
  for (int e = tid; e < C_ * P_; e += 256) {
    int c = e / P_, p = e - (e / P_) * P_;
    float b3 = bc3[c];
    float4 o = make_float4(b3, b3, b3, b3);
#pragma unroll
    for (int f = 0; f < 16; ++f) {
      float wv = w3s[c][f];
      float4 z = *(const float4*)&zs[f][p*4];
      o.x += wv * z.x; o.y += wv * z.y; o.z += wv * z.z; o.w += wv * z.w;
    }
    size_t idx = (((size_t)b * C_ + c) * P_ + p) * T_;
    float4 xr = *(const float4*)(pre1 + idx);
    float a1c = a1[c], b1c = b1[c];
    o.x += xr.x * a1c + b1c;
    o.y += xr.y * a1c + b1c;
    o.z += xr.z * a1c + b1c;
    o.w += xr.w * a1c + b1c;
    *(float4*)(pre2 + idx) = o;
  }
}

// K8: apply BN2 -> out
__global__ __launch_bounds__(256) void bnapply_kernel(
    const float* __restrict__ pre2, const float* __restrict__ a, const float* __restrict__ bs,
    float* __restrict__ out) {
  int i = blockIdx.x * 256 + threadIdx.x;
  if (i < (B_*C_*PT_)/4) {
    int row = (i * 4) / PT_;      // b*C_ + c
    int c = row % C_;
    float4 v = *(const float4*)(pre2 + (size_t)i * 4);
    float ai = a[c], bi = bs[c];
    float4 o = make_float4(v.x*ai+bi, v.y*ai+bi, v.z*ai+bi, v.w*ai+bi);
    *(float4*)(out + (size_t)i * 4) = o;
  }
}

extern "C" void kernel_launch(void* const* d_in, const int* in_sizes, int n_in,
                              void* d_out, int out_size, void* d_ws, size_t ws_size,
                              hipStream_t stream) {
  const float* x        = (const float*)d_in[0];
  const float* w_qkv    = (const float*)d_in[1];
  const float* b_qkv    = (const float*)d_in[2];
  const float* rel      = (const float*)d_in[3];
  const float* g1       = (const float*)d_in[4];
  const float* beta1    = (const float*)d_in[5];
  const float* w_c1     = (const float*)d_in[6];
  const float* bc1      = (const float*)d_in[7];
  const float* w_c2     = (const float*)d_in[8];
  const float* bc2      = (const float*)d_in[9];
  const float* g_cfe    = (const float*)d_in[10];
  const float* beta_cfe = (const float*)d_in[11];
  const float* w_c3     = (const float*)d_in[12];
  const float* bc3      = (const float*)d_in[13];
  const float* g2       = (const float*)d_in[14];
  const float* beta2    = (const float*)d_in[15];
  float* out = (float*)d_out;
  char* ws = (char*)d_ws;

  // ws layout (bytes):
  //   0          q_ws  bf16 12.7M elems (25,395,200 B)
  //   25395200   k_ws  bf16
  //   50790400   v_ws  bf16
  //   76185600   pre1  f32  (50,790,400 B)
  //   126976000  y16   f32  (3,276,800 B)
  //   130252800  rel_bf bf16 (24,552 B)
  //   130278400  stats (f32)
  //   pre2 aliases ws+0 (q+k region, dead after attention)
  unsigned short* q_ws  = (unsigned short*)(ws);
  unsigned short* k_ws  = (unsigned short*)(ws + 25395200);
  unsigned short* v_ws  = (unsigned short*)(ws + 50790400);
  float* pre1           = (float*)(ws + 76185600);
  float* y16            = (float*)(ws + 126976000);
  unsigned short* relbf = (unsigned short*)(ws + 130252800);
  float* st             = (float*)(ws + 130278400);
  float* a1 = st, *b1 = st + 256, *acf = st + 512, *bcf = st + 544, *a2 = st + 576, *b2 = st + 832;
  float* pre2           = (float*)ws;

  relcvt_kernel<<<48, 256, 0, stream>>>(rel, relbf);
  qkv_kernel<<<dim3(800, 6), 256, 0, stream>>>(x, w_qkv, b_qkv, q_ws, k_ws, v_ws);
  attn_kernel<<<2048, 256, 0, stream>>>(q_ws, k_ws, v_ws, relbf, x, pre1);
  bnstat_kernel<<<248, 256, 0, stream>>>(pre1, g1, beta1, a1, b1, C_);
  cfe12_kernel<<<256, 256, 0, stream>>>(pre1, a1, b1, w_c1, bc1, w_c2, bc2, y16);
  bnstat_kernel<<<16, 256, 0, stream>>>(y16, g_cfe, beta_cfe, acf, bcf, 16);
  cfe3_kernel<<<256, 256, 0, stream>>>(y16, acf, bcf, w_c3, bc3, pre1, a1, b1, pre2);
  bnstat_kernel<<<248, 256, 0, stream>>>(pre2, g2, beta2, a2, b2, C_);
  bnapply_kernel<<<12400, 256, 0, stream>>>(pre2, a2, b2, out);
}

// Round 2
// 653.789 us; speedup vs baseline: 1.3263x; 1.3263x over previous
//
#include <hip/hip_runtime.h>

#define B_ 256
#define C_ 248
#define P_ 50
#define T_ 4
#define H_ 8
#define D_ 31
#define DH_ 124
#define PT_ 200
#define O3_ 744

typedef __attribute__((ext_vector_type(8))) short short8v;
typedef __attribute__((ext_vector_type(4))) float f32x4;

__device__ __forceinline__ float bf2f(unsigned short u) {
  union { unsigned int i; float f; } v; v.i = ((unsigned int)u) << 16; return v.f;
}
__device__ __forceinline__ unsigned short f2bf(float f) {
  union { float f; unsigned int i; } v; v.f = f;
  unsigned int r = v.i + 0x7fffu + ((v.i >> 16) & 1u);
  return (unsigned short)(r >> 16);
}

// K0: rel_emb fp32 -> bf16, zero-padded to [112][128]
__global__ void relcvt_kernel(const float* __restrict__ rel, unsigned short* __restrict__ out) {
  int i = blockIdx.x * 256 + threadIdx.x;
  if (i < 112 * 128) {
    int r = i >> 7, k = i & 127;
    out[i] = (r < 99 && k < DH_) ? f2bf(rel[r * DH_ + k]) : (unsigned short)0;
  }
}

// K1: qkv projection GEMM. out tile 128 o x 64 s, fp32 LDS tiles, bf16 stores
__global__ __launch_bounds__(256) void qkv_kernel(
    const float* __restrict__ x, const float* __restrict__ w,
    const float* __restrict__ bias,
    unsigned short* __restrict__ q_ws, unsigned short* __restrict__ k_ws,
    unsigned short* __restrict__ v_ws) {
  __shared__ float xs[16][72];
  __shared__ float wts[16][136];
  const int tid = threadIdx.x;
  const int tx = tid & 15, ty = tid >> 4;
  const int s0 = blockIdx.x * 64;
  const int o0 = blockIdx.y * 128;
  float acc[8][4];
#pragma unroll
  for (int i = 0; i < 8; ++i) { acc[i][0]=0.f; acc[i][1]=0.f; acc[i][2]=0.f; acc[i][3]=0.f; }

  const int ls_k = ty;
  const int ls_s = tx * 4;
  const int s_l = s0 + ls_s;
  const int b_l = s_l / PT_;
  const int pt_l = s_l - b_l * PT_;
  const float* xbase = x + (size_t)b_l * C_ * PT_ + pt_l;

  const int wo = tid >> 2;
  const int wc = (tid & 3) << 2;

  for (int kc = 0; kc < 256; kc += 16) {
    int cx = kc + ls_k;
    float4 xv = make_float4(0.f,0.f,0.f,0.f);
    if (cx < C_) xv = *(const float4*)(xbase + (size_t)cx * PT_);
    float4 wv0 = make_float4(0.f,0.f,0.f,0.f);
    float4 wv1 = make_float4(0.f,0.f,0.f,0.f);
    int o_a = o0 + wo, o_b = o0 + 64 + wo;
    int cw = kc + wc;
    if (cw + 4 <= C_) {
      if (o_a < O3_) wv0 = *(const float4*)(w + (size_t)o_a * C_ + cw);
      if (o_b < O3_) wv1 = *(const float4*)(w + (size_t)o_b * C_ + cw);
    }
    __syncthreads();
    *(float4*)&xs[ls_k][ls_s] = xv;
    wts[wc+0][wo] = wv0.x; wts[wc+1][wo] = wv0.y; wts[wc+2][wo] = wv0.z; wts[wc+3][wo] = wv0.w;
    wts[wc+0][64+wo] = wv1.x; wts[wc+1][64+wo] = wv1.y; wts[wc+2][64+wo] = wv1.z; wts[wc+3][64+wo] = wv1.w;
    __syncthreads();
#pragma unroll
    for (int k = 0; k < 16; ++k) {
      float4 xv4 = *(const float4*)&xs[k][tx*4];
      float4 alo = *(const float4*)&wts[k][ty*8];
      float4 ahi = *(const float4*)&wts[k][ty*8+4];
      float a[8] = {alo.x,alo.y,alo.z,alo.w,ahi.x,ahi.y,ahi.z,ahi.w};
      float bx[4] = {xv4.x,xv4.y,xv4.z,xv4.w};
#pragma unroll
      for (int i = 0; i < 8; ++i)
#pragma unroll
        for (int j = 0; j < 4; ++j)
          acc[i][j] += a[i] * bx[j];
    }
  }
  const int sbase = s0 + tx*4;
  const int bb = sbase / PT_;
  const int pt = sbase - bb * PT_;
  const int p = pt >> 2;
#pragma unroll
  for (int i = 0; i < 8; ++i) {
    int o = o0 + ty*8 + i;
    if (o < O3_) {
      float bo = bias[o];
      int wi = o / C_;
      int r = o - wi * C_;
      int h = r / D_;
      int d = r - h * D_;
      unsigned short* dst = (wi == 0) ? q_ws : (wi == 1) ? k_ws : v_ws;
      size_t base = ((((size_t)bb * H_ + h) * P_ + p) * DH_) + (size_t)d * T_;
      ushort4 pk;
      pk.x = f2bf(acc[i][0] + bo);
      pk.y = f2bf(acc[i][1] + bo);
      pk.z = f2bf(acc[i][2] + bo);
      pk.w = f2bf(acc[i][3] + bo);
      *(ushort4*)(dst + base) = pk;
    }
  }
}

// K2: per-(b,h) MFMA attention: (QK^T + rel bias) softmax PV + residual -> pre1
// 4 waves; wave w owns M-tile rows 16w..16w+15 (p), padded M=64, Kdim=128, N(scores)=64, N(rel)=112, N(out)=128
__global__ __launch_bounds__(256) void attn_kernel(
    const unsigned short* __restrict__ q_ws, const unsigned short* __restrict__ k_ws,
    const unsigned short* __restrict__ v_ws, const unsigned short* __restrict__ relp,
    const float* __restrict__ x, float* __restrict__ pre1) {
  // XOR-swizzled (byte ^= (row&7)<<4) to kill 16-way ds_read_b128 bank conflicts (T2)
  __shared__ __align__(16) unsigned short Qs[64 * 128];   // 16KB, Q * 31^-0.5
  __shared__ __align__(16) unsigned short Ks[64 * 128];   // 16KB
  __shared__ __align__(16) unsigned short Vt[128 * 64];   // 16KB, Vt[dh][j]
  __shared__ __align__(16) unsigned short Ps[64 * 64];    // 8KB probs bf16
  __shared__ __align__(16) unsigned short brs[64 * 112];  // 14KB rel bias bf16 (unswizzled)
  const int tid = threadIdx.x;
  const int bh = blockIdx.x, b = bh >> 3, h = bh & 7;
  const size_t off = (size_t)bh * (P_ * DH_);

  // zero padding regions (whole Qs/Ks/Vt)
  {
    float4 z = make_float4(0.f, 0.f, 0.f, 0.f);
    float4* z1 = (float4*)Qs; float4* z2 = (float4*)Ks; float4* z3 = (float4*)Vt;
    for (int i = tid; i < 1024; i += 256) { z1[i] = z; z2[i] = z; z3[i] = z; }
  }
  __syncthreads();
  // stage Q (scaled), K, V^T
  const float scale = 0.17960530202677491f;
  for (int i = tid; i < 1550; i += 256) {  // 50 rows * 31 ushort4
    int p = i / 31, kq = (i - p * 31) * 4;
    ushort4 qv = *(const ushort4*)(q_ws + off + p * DH_ + kq);
    qv.x = f2bf(bf2f(qv.x) * scale); qv.y = f2bf(bf2f(qv.y) * scale);
    qv.z = f2bf(bf2f(qv.z) * scale); qv.w = f2bf(bf2f(qv.w) * scale);
    *(ushort4*)((char*)Qs + ((p * 256 + kq * 2) ^ ((p & 7) << 4))) = qv;
    ushort4 kv = *(const ushort4*)(k_ws + off + p * DH_ + kq);
    *(ushort4*)((char*)Ks + ((p * 256 + kq * 2) ^ ((p & 7) << 4))) = kv;
    ushort4 vv = *(const ushort4*)(v_ws + off + p * DH_ + kq);
    unsigned short ve[4] = {vv.x, vv.y, vv.z, vv.w};
#pragma unroll
    for (int e = 0; e < 4; ++e) {
      int dh = kq + e;
      *(unsigned short*)((char*)Vt + ((dh * 128 + p * 2) ^ ((dh & 7) << 4))) = ve[e];
    }
  }
  __syncthreads();

  const int w = tid >> 6, l = tid & 63;
  const int lr = l & 15;              // A row / B col within tile
  const int lk = (l >> 4) * 8;        // k-chunk base
  const int arow = 16 * w + lr;
  const int prow0 = 16 * w + (l >> 4) * 4;  // C/D: row = (lane>>4)*4 + reg

  const f32x4 zf = {0.f, 0.f, 0.f, 0.f};
  f32x4 accS[4]; f32x4 accR[7];
#pragma unroll
  for (int n = 0; n < 4; ++n) accS[n] = zf;
#pragma unroll
  for (int n = 0; n < 7; ++n) accR[n] = zf;

#pragma unroll
  for (int ks = 0; ks < 4; ++ks) {
    int k0 = ks * 32 + lk;
    short8v a = *(const short8v*)((const char*)Qs + ((arow * 256 + 2 * k0) ^ ((arow & 7) << 4)));
#pragma unroll
    for (int n = 0; n < 4; ++n) {
      int brow = 16 * n + lr;
      short8v bb = *(const short8v*)((const char*)Ks + ((brow * 256 + 2 * k0) ^ ((brow & 7) << 4)));
      accS[n] = __builtin_amdgcn_mfma_f32_16x16x32_bf16(a, bb, accS[n], 0, 0, 0);
    }
#pragma unroll
    for (int n = 0; n < 7; ++n) {
      int rrow = 16 * n + lr;
      short8v bb = *(const short8v*)(relp + rrow * 128 + k0);  // L2-resident, 16B aligned
      accR[n] = __builtin_amdgcn_mfma_f32_16x16x32_bf16(a, bb, accR[n], 0, 0, 0);
    }
  }
  // spill brel to LDS (need cross-lane gather for the diagonal shift)
#pragma unroll
  for (int n = 0; n < 7; ++n)
#pragma unroll
    for (int r = 0; r < 4; ++r)
      brs[(prow0 + r) * 112 + 16 * n + lr] = f2bf(accR[n][r]);
  __syncthreads();

  // bias add + mask + row softmax (rows spread over 16-lane groups)
  float sv[4][4];
#pragma unroll
  for (int n = 0; n < 4; ++n)
#pragma unroll
    for (int r = 0; r < 4; ++r) {
      int p = prow0 + r, j = 16 * n + lr;
      if (p < P_ && j < P_)
        sv[n][r] = accS[n][r] + bf2f(brs[p * 112 + (49 + j - p)]);
      else
        sv[n][r] = -1e30f;
    }
#pragma unroll
  for (int r = 0; r < 4; ++r) {
    float mm = fmaxf(fmaxf(sv[0][r], sv[1][r]), fmaxf(sv[2][r], sv[3][r]));
    mm = fmaxf(mm, __shfl_xor(mm, 1));
    mm = fmaxf(mm, __shfl_xor(mm, 2));
    mm = fmaxf(mm, __shfl_xor(mm, 4));
    mm = fmaxf(mm, __shfl_xor(mm, 8));
    float ss = 0.f;
#pragma unroll
    for (int n = 0; n < 4; ++n) { float e = __expf(sv[n][r] - mm); sv[n][r] = e; ss += e; }
    ss += __shfl_xor(ss, 1); ss += __shfl_xor(ss, 2);
    ss += __shfl_xor(ss, 4); ss += __shfl_xor(ss, 8);
    float inv = 1.f / ss;
#pragma unroll
    for (int n = 0; n < 4; ++n) sv[n][r] *= inv;
  }
#pragma unroll
  for (int n = 0; n < 4; ++n)
#pragma unroll
    for (int r = 0; r < 4; ++r) {
      int p = prow0 + r, j = 16 * n + lr;
      *(unsigned short*)((char*)Ps + ((p * 128 + 2 * j) ^ ((p & 7) << 4))) = f2bf(sv[n][r]);
    }
  __syncthreads();

  // PV
  f32x4 accO[8];
#pragma unroll
  for (int n = 0; n < 8; ++n) accO[n] = zf;
#pragma unroll
  for (int ks = 0; ks < 2; ++ks) {
    int j0 = ks * 32 + lk;
    short8v a = *(const short8v*)((const char*)Ps + ((arow * 128 + 2 * j0) ^ ((arow & 7) << 4)));
#pragma unroll
    for (int n = 0; n < 8; ++n) {
      int vrow = 16 * n + lr;
      short8v bb = *(const short8v*)((const char*)Vt + ((vrow * 128 + 2 * j0) ^ ((vrow & 7) << 4)));
      accO[n] = __builtin_amdgcn_mfma_f32_16x16x32_bf16(a, bb, accO[n], 0, 0, 0);
    }
  }
  // epilogue: + x residual -> pre1
#pragma unroll
  for (int n = 0; n < 8; ++n) {
    int dh = 16 * n + lr;
    if (dh < DH_) {
      int c = h * D_ + (dh >> 2), t = dh & 3;
#pragma unroll
      for (int r = 0; r < 4; ++r) {
        int p = prow0 + r;
        if (p < P_) {
          size_t idx = (((size_t)b * C_ + c) * P_ + p) * T_ + t;
          pre1[idx] = accO[n][r] + x[idx];
        }
      }
    }
  }
}

// BN batch-stat reduction: per channel over (B, PT). 256 threads = one b each.
__global__ __launch_bounds__(256) void bnstat_kernel(
    const float* __restrict__ t, const float* __restrict__ g, const float* __restrict__ be,
    float* __restrict__ a, float* __restrict__ bs, int nch) {
  const int c = blockIdx.x;
  const int tid = threadIdx.x;
  const float* base = t + ((size_t)tid * nch + c) * PT_;
  float s = 0.f, s2 = 0.f;
  for (int i = 0; i < PT_; i += 4) {
    float4 v = *(const float4*)(base + i);
    s += v.x + v.y + v.z + v.w;
    s2 += v.x*v.x + v.y*v.y + v.z*v.z + v.w*v.w;
  }
#pragma unroll
  for (int off = 32; off > 0; off >>= 1) {
    s += __shfl_down(s, off);
    s2 += __shfl_down(s2, off);
  }
  __shared__ float r1[4], r2[4];
  if ((tid & 63) == 0) { r1[tid>>6] = s; r2[tid>>6] = s2; }
  __syncthreads();
  if (tid == 0) {
    s = r1[0]+r1[1]+r1[2]+r1[3];
    s2 = r2[0]+r2[1]+r2[2]+r2[3];
    const float inv = 1.f / (float)(B_ * PT_);
    float m = s * inv;
    float var = s2 * inv - m * m;
    float ai = g[c] * rsqrtf(var + 1e-5f);
    a[c] = ai;
    bs[c] = be[c] - m * ai;
  }
}

// K4: conv1(1x3) + conv2(1x5) over BN1(pre1), one block per b
__global__ __launch_bounds__(256) void cfe12_kernel(
    const float* __restrict__ pre1, const float* __restrict__ a1, const float* __restrict__ b1,
    const float* __restrict__ w1, const float* __restrict__ bc1,
    const float* __restrict__ w2, const float* __restrict__ bc2,
    float* __restrict__ y16) {
  const int b = blockIdx.x;
  const int tid = threadIdx.x;
  __shared__ unsigned short xs[62][PT_];
  __shared__ unsigned short w1s[8*C_*3];
  __shared__ unsigned short w2s[8*C_*5];
  for (int i = tid; i < 8*C_*3; i += 256) w1s[i] = f2bf(w1[i]);
  for (int i = tid; i < 8*C_*5; i += 256) w2s[i] = f2bf(w2[i]);
  float acc[4][4];
#pragma unroll
  for (int l = 0; l < 4; ++l) { acc[l][0]=0.f; acc[l][1]=0.f; acc[l][2]=0.f; acc[l][3]=0.f; }
  for (int cc = 0; cc < C_; cc += 62) {
    __syncthreads();
    for (int e = tid; e < 62*PT_; e += 256) {
      int cl = e / PT_, pt = e - cl * PT_;
      int c = cc + cl;
      float v = pre1[((size_t)b * C_ + c) * PT_ + pt];
      xs[cl][pt] = f2bf(v * a1[c] + b1[c]);
    }
    __syncthreads();
    for (int l = 0; l < 4; ++l) {
      int u = tid + l * 256;
      if (u >= 800) break;
      int f = u / P_, p = u - (u / P_) * P_;
      if (f < 8) {
        const unsigned short* wp = w1s + (f * C_ + cc) * 3;
        for (int cl = 0; cl < 62; ++cl) {
          ushort4 x4 = *(const ushort4*)&xs[cl][p*4];
          float x0=bf2f(x4.x), x1=bf2f(x4.y), x2=bf2f(x4.z), x3=bf2f(x4.w);
          float w0=bf2f(wp[cl*3]), w1v=bf2f(wp[cl*3+1]), w2v=bf2f(wp[cl*3+2]);
          acc[l][0] += x0*w1v + x1*w2v;
          acc[l][1] += x0*w0 + x1*w1v + x2*w2v;
          acc[l][2] += x1*w0 + x2*w1v + x3*w2v;
          acc[l][3] += x2*w0 + x3*w1v;
        }
      } else {
        const unsigned short* wp = w2s + ((f-8) * C_ + cc) * 5;
        for (int cl = 0; cl < 62; ++cl) {
          ushort4 x4 = *(const ushort4*)&xs[cl][p*4];
          float x0=bf2f(x4.x), x1=bf2f(x4.y), x2=bf2f(x4.z), x3=bf2f(x4.w);
          float w0=bf2f(wp[cl*5]), w1v=bf2f(wp[cl*5+1]), w2v=bf2f(wp[cl*5+2]);
          float w3v=bf2f(wp[cl*5+3]), w4v=bf2f(wp[cl*5+4]);
          acc[l][0] += x0*w2v + x1*w3v + x2*w4v;
          acc[l][1] += x0*w1v + x1*w2v + x2*w3v + x3*w4v;
          acc[l][2] += x0*w0 + x1*w1v + x2*w2v + x3*w3v;
          acc[l][3] += x1*w0 + x2*w1v + x3*w2v;
        }
      }
    }
  }
  for (int l = 0; l < 4; ++l) {
    int u = tid + l * 256;
    if (u >= 800) break;
    int f = u / P_, p = u - (u / P_) * P_;
    float bias = (f < 8) ? bc1[f] : bc2[f-8];
    float4 o = make_float4(acc[l][0]+bias, acc[l][1]+bias, acc[l][2]+bias, acc[l][3]+bias);
    *(float4*)(y16 + ((size_t)b * 16 + f) * PT_ + p*4) = o;
  }
}

// K6: ELU(BN_cfe(y16)) -> conv3 (16->248) + BN1-residual -> pre2
__global__ __launch_bounds__(256) void cfe3_kernel(
    const float* __restrict__ y16, const float* __restrict__ ac, const float* __restrict__ bcf,
    const float* __restrict__ w3, const float* __restrict__ bc3,
    const float* __restrict__ pre1, const float* __restrict__ a1, const float* __restrict__ b1,
    float* __restrict__ pre2) {
  const int b = blockIdx.x;
  const int tid = threadIdx.x;
  __shared__ float zs[16][PT_];
  __shared__ float w3s[C_][16];
  for (int i = tid; i < C_*16; i += 256) w3s[i >> 4][i & 15] = w3[i];
  for (int e = tid; e < 16*PT_; e += 256) {
    int f = e / PT_, pt = e - f * PT_;
    float v = y16[((size_t)b*16 + f) * PT_ + pt] * ac[f] + bcf[f];
    zs[f][pt] = (v > 0.f) ? v : (__expf(v) - 1.f);
  }
  __syncthreads();
  for (int e = tid; e < C_ * P_; e += 256) {
    int c = e / P_, p = e - (e / P_) * P_;
    float b3 = bc3[c];
    float4 o = make_float4(b3, b3, b3, b3);
#pragma unroll
    for (int f = 0; f < 16; ++f) {
      float wv = w3s[c][f];
      float4 z = *(const float4*)&zs[f][p*4];
      o.x += wv * z.x; o.y += wv * z.y; o.z += wv * z.z; o.w += wv * z.w;
    }
    size_t idx = (((size_t)b * C_ + c) * P_ + p) * T_;
    float4 xr = *(const float4*)(pre1 + idx);
    float a1c = a1[c], b1c = b1[c];
    o.x += xr.x * a1c + b1c;
    o.y += xr.y * a1c + b1c;
    o.z += xr.z * a1c + b1c;
    o.w += xr.w * a1c + b1c;
    *(float4*)(pre2 + idx) = o;
  }
}

// K8: apply BN2 -> out
__global__ __launch_bounds__(256) void bnapply_kernel(
    const float* __restrict__ pre2, const float* __restrict__ a, const float* __restrict__ bs,
    float* __restrict__ out) {
  int i = blockIdx.x * 256 + threadIdx.x;
  if (i < (B_*C_*PT_)/4) {
    int row = (i * 4) / PT_;
    int c = row % C_;
    float4 v = *(const float4*)(pre2 + (size_t)i * 4);
    float ai = a[c], bi = bs[c];
    float4 o = make_float4(v.x*ai+bi, v.y*ai+bi, v.z*ai+bi, v.w*ai+bi);
    *(float4*)(out + (size_t)i * 4) = o;
  }
}

extern "C" void kernel_launch(void* const* d_in, const int* in_sizes, int n_in,
                              void* d_out, int out_size, void* d_ws, size_t ws_size,
                              hipStream_t stream) {
  const float* x        = (const float*)d_in[0];
  const float* w_qkv    = (const float*)d_in[1];
  const float* b_qkv    = (const float*)d_in[2];
  const float* rel      = (const float*)d_in[3];
  const float* g1       = (const float*)d_in[4];
  const float* beta1    = (const float*)d_in[5];
  const float* w_c1     = (const float*)d_in[6];
  const float* bc1      = (const float*)d_in[7];
  const float* w_c2     = (const float*)d_in[8];
  const float* bc2      = (const float*)d_in[9];
  const float* g_cfe    = (const float*)d_in[10];
  const float* beta_cfe = (const float*)d_in[11];
  const float* w_c3     = (const float*)d_in[12];
  const float* bc3      = (const float*)d_in[13];
  const float* g2       = (const float*)d_in[14];
  const float* beta2    = (const float*)d_in[15];
  float* out = (float*)d_out;
  char* ws = (char*)d_ws;

  // ws layout (bytes):
  //   0          q_ws bf16 (25,395,200)   [pre2 f32 aliases q+k after attn]
  //   25395200   k_ws bf16
  //   50790400   v_ws bf16
  //   76185600   pre1 f32 (50,790,400)
  //   126976000  y16  f32 (3,276,800)
  //   130252800  relp bf16 padded [112][128] (28,672)
  //   130281472  stats f32
  unsigned short* q_ws  = (unsigned short*)(ws);
  unsigned short* k_ws  = (unsigned short*)(ws + 25395200);
  unsigned short* v_ws  = (unsigned short*)(ws + 50790400);
  float* pre1           = (float*)(ws + 76185600);
  float* y16            = (float*)(ws + 126976000);
  unsigned short* relp  = (unsigned short*)(ws + 130252800);
  float* st             = (float*)(ws + 130281472);
  float* a1 = st, *b1 = st + 256, *acf = st + 512, *bcf = st + 544, *a2 = st + 576, *b2 = st + 832;
  float* pre2           = (float*)ws;

  relcvt_kernel<<<56, 256, 0, stream>>>(rel, relp);
  qkv_kernel<<<dim3(800, 6), 256, 0, stream>>>(x, w_qkv, b_qkv, q_ws, k_ws, v_ws);
  attn_kernel<<<2048, 256, 0, stream>>>(q_ws, k_ws, v_ws, relp, x, pre1);
  bnstat_kernel<<<248, 256, 0, stream>>>(pre1, g1, beta1, a1, b1, C_);
  cfe12_kernel<<<256, 256, 0, stream>>>(pre1, a1, b1, w_c1, bc1, w_c2, bc2, y16);
  bnstat_kernel<<<16, 256, 0, stream>>>(y16, g_cfe, beta_cfe, acf, bcf, 16);
  cfe3_kernel<<<256, 256, 0, stream>>>(y16, acf, bcf, w_c3, bc3, pre1, a1, b1, pre2);
  bnstat_kernel<<<248, 256, 0, stream>>>(pre2, g2, beta2, a2, b2, C_);
  bnapply_kernel<<<12400, 256, 0, stream>>>(pre2, a2, b2, out);
}

// Round 4
// 506.400 us; speedup vs baseline: 1.7123x; 1.2911x over previous
//
#include <hip/hip_runtime.h>

#define B_ 256
#define C_ 248
#define P_ 50
#define T_ 4
#define H_ 8
#define D_ 31
#define DH_ 124
#define PT_ 200
#define O3_ 744

typedef __attribute__((ext_vector_type(8))) short short8v;
typedef __attribute__((ext_vector_type(4))) float f32x4;

__device__ __forceinline__ float bf2f(unsigned short u) {
  union { unsigned int i; float f; } v; v.i = ((unsigned int)u) << 16; return v.f;
}
__device__ __forceinline__ unsigned short f2bf(float f) {
  union { float f; unsigned int i; } v; v.f = f;
  unsigned int r = v.i + 0x7fffu + ((v.i >> 16) & 1u);
  return (unsigned short)(r >> 16);
}

// K0: rel_emb fp32 -> bf16, zero-padded to [112][128]
__global__ void relcvt_kernel(const float* __restrict__ rel, unsigned short* __restrict__ out) {
  int i = blockIdx.x * 256 + threadIdx.x;
  if (i < 112 * 128) {
    int r = i >> 7, k = i & 127;
    out[i] = (r < 99 && k < DH_) ? f2bf(rel[r * DH_ + k]) : (unsigned short)0;
  }
}

// K0b: w_qkv fp32 [744][248] -> bf16 zero-padded [768][256]
__global__ void wcvt_kernel(const float* __restrict__ w, unsigned short* __restrict__ wbf) {
  int i = blockIdx.x * 256 + threadIdx.x;  // 768*64 ushort4 slots
  if (i < 768 * 64) {
    int o = i >> 6, c = (i & 63) * 4;
    ushort4 val = make_ushort4(0, 0, 0, 0);
    if (o < O3_ && c < C_) {
      float4 wv = *(const float4*)(w + (size_t)o * C_ + c);
      val.x = f2bf(wv.x); val.y = f2bf(wv.y); val.z = f2bf(wv.z); val.w = f2bf(wv.w);
    }
    *(ushort4*)(wbf + (size_t)o * 256 + c) = val;
  }
}

// K0c: x fp32 [b][248][200] -> xT bf16 [b][208][256] (pt-major, zero-padded)
__global__ __launch_bounds__(256) void xt_kernel(const float* __restrict__ x,
                                                 unsigned short* __restrict__ xT) {
  __shared__ float xs[64 * 65];
  const int tid = threadIdx.x;
  const int pt0 = (blockIdx.x & 3) * 64;
  const int c0 = (blockIdx.x >> 2) * 64;
  const int b = blockIdx.y;
#pragma unroll
  for (int pass = 0; pass < 4; ++pass) {
    int row = pass * 16 + (tid >> 4);       // c local
    int ptl4 = (tid & 15) * 4;              // pt local
    int c = c0 + row, pt = pt0 + ptl4;
    float4 v = make_float4(0.f, 0.f, 0.f, 0.f);
    if (c < C_) {
      const float* src = x + ((size_t)b * C_ + c) * PT_ + pt;
      if (pt + 3 < PT_) v = *(const float4*)src;
      else {
        if (pt + 0 < PT_) v.x = src[0];
        if (pt + 1 < PT_) v.y = src[1];
        if (pt + 2 < PT_) v.z = src[2];
        if (pt + 3 < PT_) v.w = src[3];
      }
    }
    xs[row * 65 + ptl4 + 0] = v.x; xs[row * 65 + ptl4 + 1] = v.y;
    xs[row * 65 + ptl4 + 2] = v.z; xs[row * 65 + ptl4 + 3] = v.w;
  }
  __syncthreads();
#pragma unroll
  for (int pass = 0; pass < 4; ++pass) {
    int ptl = pass * 16 + (tid >> 4);
    int cl4 = (tid & 15) * 4;
    int pt = pt0 + ptl;
    if (pt < 208) {
      ushort4 pk;
      pk.x = f2bf(xs[(cl4 + 0) * 65 + ptl]);
      pk.y = f2bf(xs[(cl4 + 1) * 65 + ptl]);
      pk.z = f2bf(xs[(cl4 + 2) * 65 + ptl]);
      pk.w = f2bf(xs[(cl4 + 3) * 65 + ptl]);
      *(ushort4*)(xT + ((size_t)b * 208 + pt) * 256 + c0 + cl4) = pk;
    }
  }
}

// K1: MFMA qkv GEMM. Per block: b, 128-o tile. M=pt (13x16 from xT), N=o (2x16/wave), K=256.
// A-frags global-direct from xT (L2), B-frags global-direct from wbf (L2). No LDS.
__global__ __launch_bounds__(256) void qkv_mfma_kernel(
    const unsigned short* __restrict__ xT, const unsigned short* __restrict__ wbf,
    const float* __restrict__ bias,
    unsigned short* __restrict__ q_ws, unsigned short* __restrict__ k_ws,
    unsigned short* __restrict__ v_ws) {
  const int tid = threadIdx.x;
  const int w = tid >> 6, l = tid & 63;
  const int lr = l & 15, lk = (l >> 4) * 8;
  const int b = blockIdx.y;
  const int o_w = blockIdx.x * 128 + w * 32;   // this wave's first 16-o tile
  const unsigned short* xb = xT + (size_t)b * 208 * 256;

  const f32x4 zf = {0.f, 0.f, 0.f, 0.f};
  f32x4 acc0[13], acc1[13];
#pragma unroll
  for (int m = 0; m < 13; ++m) { acc0[m] = zf; acc1[m] = zf; }

#pragma unroll
  for (int ks = 0; ks < 8; ++ks) {
    int k0 = ks * 32 + lk;
    short8v b0 = *(const short8v*)(wbf + (size_t)(o_w + lr) * 256 + k0);
    short8v b1 = *(const short8v*)(wbf + (size_t)(o_w + 16 + lr) * 256 + k0);
#pragma unroll
    for (int m = 0; m < 13; ++m) {
      short8v a = *(const short8v*)(xb + (size_t)(m * 16 + lr) * 256 + k0);
      acc0[m] = __builtin_amdgcn_mfma_f32_16x16x32_bf16(a, b0, acc0[m], 0, 0, 0);
      acc1[m] = __builtin_amdgcn_mfma_f32_16x16x32_bf16(a, b1, acc1[m], 0, 0, 0);
    }
  }
#pragma unroll
  for (int n = 0; n < 2; ++n) {
    int o = o_w + n * 16 + lr;
    if (o < O3_) {
      float bo = bias[o];
      int wi = o / C_;
      int rem = o - wi * C_;
      int h = rem / D_;
      int d = rem - h * D_;
      unsigned short* dst = (wi == 0) ? q_ws : (wi == 1) ? k_ws : v_ws;
      size_t rowb = ((size_t)b * H_ + h) * P_;
#pragma unroll
      for (int m = 0; m < 13; ++m) {
        int p = 4 * m + (l >> 4);
        if (p < P_) {
          f32x4 av = (n == 0) ? acc0[m] : acc1[m];
          ushort4 pk;
          pk.x = f2bf(av[0] + bo); pk.y = f2bf(av[1] + bo);
          pk.z = f2bf(av[2] + bo); pk.w = f2bf(av[3] + bo);
          *(ushort4*)(dst + (rowb + p) * DH_ + d * T_) = pk;
        }
      }
    }
  }
}

// K2: per-(b,h) MFMA attention: (QK^T + rel bias) softmax PV + residual -> pre1
__global__ __launch_bounds__(256) void attn_kernel(
    const unsigned short* __restrict__ q_ws, const unsigned short* __restrict__ k_ws,
    const unsigned short* __restrict__ v_ws, const unsigned short* __restrict__ relp,
    const float* __restrict__ x, float* __restrict__ pre1) {
  __shared__ __align__(16) unsigned short Qs[64 * 128];
  __shared__ __align__(16) unsigned short Ks[64 * 128];
  __shared__ __align__(16) unsigned short Vt[128 * 64];
  __shared__ __align__(16) unsigned short Ps[64 * 64];
  __shared__ __align__(16) unsigned short brs[64 * 112];
  const int tid = threadIdx.x;
  const int bh = blockIdx.x, b = bh >> 3, h = bh & 7;
  const size_t off = (size_t)bh * (P_ * DH_);

  {
    float4 z = make_float4(0.f, 0.f, 0.f, 0.f);
    float4* z1 = (float4*)Qs; float4* z2 = (float4*)Ks; float4* z3 = (float4*)Vt;
    for (int i = tid; i < 1024; i += 256) { z1[i] = z; z2[i] = z; z3[i] = z; }
  }
  __syncthreads();
  const float scale = 0.17960530202677491f;
  for (int i = tid; i < 1550; i += 256) {
    int p = i / 31, kq = (i - p * 31) * 4;
    ushort4 qv = *(const ushort4*)(q_ws + off + p * DH_ + kq);
    qv.x = f2bf(bf2f(qv.x) * scale); qv.y = f2bf(bf2f(qv.y) * scale);
    qv.z = f2bf(bf2f(qv.z) * scale); qv.w = f2bf(bf2f(qv.w) * scale);
    *(ushort4*)((char*)Qs + ((p * 256 + kq * 2) ^ ((p & 7) << 4))) = qv;
    ushort4 kv = *(const ushort4*)(k_ws + off + p * DH_ + kq);
    *(ushort4*)((char*)Ks + ((p * 256 + kq * 2) ^ ((p & 7) << 4))) = kv;
    ushort4 vv = *(const ushort4*)(v_ws + off + p * DH_ + kq);
    unsigned short ve[4] = {vv.x, vv.y, vv.z, vv.w};
#pragma unroll
    for (int e = 0; e < 4; ++e) {
      int dh = kq + e;
      *(unsigned short*)((char*)Vt + ((dh * 128 + p * 2) ^ ((dh & 7) << 4))) = ve[e];
    }
  }
  __syncthreads();

  const int w = tid >> 6, l = tid & 63;
  const int lr = l & 15;
  const int lk = (l >> 4) * 8;
  const int arow = 16 * w + lr;
  const int prow0 = 16 * w + (l >> 4) * 4;

  const f32x4 zf = {0.f, 0.f, 0.f, 0.f};
  f32x4 accS[4]; f32x4 accR[7];
#pragma unroll
  for (int n = 0; n < 4; ++n) accS[n] = zf;
#pragma unroll
  for (int n = 0; n < 7; ++n) accR[n] = zf;

#pragma unroll
  for (int ks = 0; ks < 4; ++ks) {
    int k0 = ks * 32 + lk;
    short8v a = *(const short8v*)((const char*)Qs + ((arow * 256 + 2 * k0) ^ ((arow & 7) << 4)));
#pragma unroll
    for (int n = 0; n < 4; ++n) {
      int brow = 16 * n + lr;
      short8v bb = *(const short8v*)((const char*)Ks + ((brow * 256 + 2 * k0) ^ ((brow & 7) << 4)));
      accS[n] = __builtin_amdgcn_mfma_f32_16x16x32_bf16(a, bb, accS[n], 0, 0, 0);
    }
#pragma unroll
    for (int n = 0; n < 7; ++n) {
      int rrow = 16 * n + lr;
      short8v bb = *(const short8v*)(relp + rrow * 128 + k0);
      accR[n] = __builtin_amdgcn_mfma_f32_16x16x32_bf16(a, bb, accR[n], 0, 0, 0);
    }
  }
#pragma unroll
  for (int n = 0; n < 7; ++n)
#pragma unroll
    for (int r = 0; r < 4; ++r)
      brs[(prow0 + r) * 112 + 16 * n + lr] = f2bf(accR[n][r]);
  __syncthreads();

  float sv[4][4];
#pragma unroll
  for (int n = 0; n < 4; ++n)
#pragma unroll
    for (int r = 0; r < 4; ++r) {
      int p = prow0 + r, j = 16 * n + lr;
      if (p < P_ && j < P_)
        sv[n][r] = accS[n][r] + bf2f(brs[p * 112 + (49 + j - p)]);
      else
        sv[n][r] = -1e30f;
    }
#pragma unroll
  for (int r = 0; r < 4; ++r) {
    float mm = fmaxf(fmaxf(sv[0][r], sv[1][r]), fmaxf(sv[2][r], sv[3][r]));
    mm = fmaxf(mm, __shfl_xor(mm, 1));
    mm = fmaxf(mm, __shfl_xor(mm, 2));
    mm = fmaxf(mm, __shfl_xor(mm, 4));
    mm = fmaxf(mm, __shfl_xor(mm, 8));
    float ss = 0.f;
#pragma unroll
    for (int n = 0; n < 4; ++n) { float e = __expf(sv[n][r] - mm); sv[n][r] = e; ss += e; }
    ss += __shfl_xor(ss, 1); ss += __shfl_xor(ss, 2);
    ss += __shfl_xor(ss, 4); ss += __shfl_xor(ss, 8);
    float inv = 1.f / ss;
#pragma unroll
    for (int n = 0; n < 4; ++n) sv[n][r] *= inv;
  }
#pragma unroll
  for (int n = 0; n < 4; ++n)
#pragma unroll
    for (int r = 0; r < 4; ++r) {
      int p = prow0 + r, j = 16 * n + lr;
      *(unsigned short*)((char*)Ps + ((p * 128 + 2 * j) ^ ((p & 7) << 4))) = f2bf(sv[n][r]);
    }
  __syncthreads();

  f32x4 accO[8];
#pragma unroll
  for (int n = 0; n < 8; ++n) accO[n] = zf;
#pragma unroll
  for (int ks = 0; ks < 2; ++ks) {
    int j0 = ks * 32 + lk;
    short8v a = *(const short8v*)((const char*)Ps + ((arow * 128 + 2 * j0) ^ ((arow & 7) << 4)));
#pragma unroll
    for (int n = 0; n < 8; ++n) {
      int vrow = 16 * n + lr;
      short8v bb = *(const short8v*)((const char*)Vt + ((vrow * 128 + 2 * j0) ^ ((vrow & 7) << 4)));
      accO[n] = __builtin_amdgcn_mfma_f32_16x16x32_bf16(a, bb, accO[n], 0, 0, 0);
    }
  }
#pragma unroll
  for (int n = 0; n < 8; ++n) {
    int dh = 16 * n + lr;
    if (dh < DH_) {
      int c = h * D_ + (dh >> 2), t = dh & 3;
#pragma unroll
      for (int r = 0; r < 4; ++r) {
        int p = prow0 + r;
        if (p < P_) {
          size_t idx = (((size_t)b * C_ + c) * P_ + p) * T_ + t;
          pre1[idx] = accO[n][r] + x[idx];
        }
      }
    }
  }
}

// BN batch-stat reduction: per channel over (B, PT). 256 threads = one b each.
__global__ __launch_bounds__(256) void bnstat_kernel(
    const float* __restrict__ t, const float* __restrict__ g, const float* __restrict__ be,
    float* __restrict__ a, float* __restrict__ bs, int nch) {
  const int c = blockIdx.x;
  const int tid = threadIdx.x;
  const float* base = t + ((size_t)tid * nch + c) * PT_;
  float s = 0.f, s2 = 0.f;
  for (int i = 0; i < PT_; i += 4) {
    float4 v = *(const float4*)(base + i);
    s += v.x + v.y + v.z + v.w;
    s2 += v.x*v.x + v.y*v.y + v.z*v.z + v.w*v.w;
  }
#pragma unroll
  for (int off = 32; off > 0; off >>= 1) {
    s += __shfl_down(s, off);
    s2 += __shfl_down(s2, off);
  }
  __shared__ float r1[4], r2[4];
  if ((tid & 63) == 0) { r1[tid>>6] = s; r2[tid>>6] = s2; }
  __syncthreads();
  if (tid == 0) {
    s = r1[0]+r1[1]+r1[2]+r1[3];
    s2 = r2[0]+r2[1]+r2[2]+r2[3];
    const float inv = 1.f / (float)(B_ * PT_);
    float m = s * inv;
    float var = s2 * inv - m * m;
    float ai = g[c] * rsqrtf(var + 1e-5f);
    a[c] = ai;
    bs[c] = be[c] - m * ai;
  }
}

// K4: conv1(1x3) + conv2(1x5) over BN1(pre1), one block per b
__global__ __launch_bounds__(256) void cfe12_kernel(
    const float* __restrict__ pre1, const float* __restrict__ a1, const float* __restrict__ b1,
    const float* __restrict__ w1, const float* __restrict__ bc1,
    const float* __restrict__ w2, const float* __restrict__ bc2,
    float* __restrict__ y16) {
  const int b = blockIdx.x;
  const int tid = threadIdx.x;
  __shared__ unsigned short xs[62][PT_];
  __shared__ unsigned short w1s[8*C_*3];
  __shared__ unsigned short w2s[8*C_*5];
  for (int i = tid; i < 8*C_*3; i += 256) w1s[i] = f2bf(w1[i]);
  for (int i = tid; i < 8*C_*5; i += 256) w2s[i] = f2bf(w2[i]);
  float acc[4][4];
#pragma unroll
  for (int l = 0; l < 4; ++l) { acc[l][0]=0.f; acc[l][1]=0.f; acc[l][2]=0.f; acc[l][3]=0.f; }
  for (int cc = 0; cc < C_; cc += 62) {
    __syncthreads();
    for (int e = tid; e < 62*PT_; e += 256) {
      int cl = e / PT_, pt = e - cl * PT_;
      int c = cc + cl;
      float v = pre1[((size_t)b * C_ + c) * PT_ + pt];
      xs[cl][pt] = f2bf(v * a1[c] + b1[c]);
    }
    __syncthreads();
    for (int l = 0; l < 4; ++l) {
      int u = tid + l * 256;
      if (u >= 800) break;
      int f = u / P_, p = u - (u / P_) * P_;
      if (f < 8) {
        const unsigned short* wp = w1s + (f * C_ + cc) * 3;
        for (int cl = 0; cl < 62; ++cl) {
          ushort4 x4 = *(const ushort4*)&xs[cl][p*4];
          float x0=bf2f(x4.x), x1=bf2f(x4.y), x2=bf2f(x4.z), x3=bf2f(x4.w);
          float w0=bf2f(wp[cl*3]), w1v=bf2f(wp[cl*3+1]), w2v=bf2f(wp[cl*3+2]);
          acc[l][0] += x0*w1v + x1*w2v;
          acc[l][1] += x0*w0 + x1*w1v + x2*w2v;
          acc[l][2] += x1*w0 + x2*w1v + x3*w2v;
          acc[l][3] += x2*w0 + x3*w1v;
        }
      } else {
        const unsigned short* wp = w2s + ((f-8) * C_ + cc) * 5;
        for (int cl = 0; cl < 62; ++cl) {
          ushort4 x4 = *(const ushort4*)&xs[cl][p*4];
          float x0=bf2f(x4.x), x1=bf2f(x4.y), x2=bf2f(x4.z), x3=bf2f(x4.w);
          float w0=bf2f(wp[cl*5]), w1v=bf2f(wp[cl*5+1]), w2v=bf2f(wp[cl*5+2]);
          float w3v=bf2f(wp[cl*5+3]), w4v=bf2f(wp[cl*5+4]);
          acc[l][0] += x0*w2v + x1*w3v + x2*w4v;
          acc[l][1] += x0*w1v + x1*w2v + x2*w3v + x3*w4v;
          acc[l][2] += x0*w0 + x1*w1v + x2*w2v + x3*w3v;
          acc[l][3] += x1*w0 + x2*w1v + x3*w2v;
        }
      }
    }
  }
  for (int l = 0; l < 4; ++l) {
    int u = tid + l * 256;
    if (u >= 800) break;
    int f = u / P_, p = u - (u / P_) * P_;
    float bias = (f < 8) ? bc1[f] : bc2[f-8];
    float4 o = make_float4(acc[l][0]+bias, acc[l][1]+bias, acc[l][2]+bias, acc[l][3]+bias);
    *(float4*)(y16 + ((size_t)b * 16 + f) * PT_ + p*4) = o;
  }
}

// K6: ELU(BN_cfe(y16)) -> conv3 (16->248) + BN1-residual -> pre2
__global__ __launch_bounds__(256) void cfe3_kernel(
    const float* __restrict__ y16, const float* __restrict__ ac, const float* __restrict__ bcf,
    const float* __restrict__ w3, const float* __restrict__ bc3,
    const float* __restrict__ pre1, const float* __restrict__ a1, const float* __restrict__ b1,
    float* __restrict__ pre2) {
  const int b = blockIdx.x;
  const int tid = threadIdx.x;
  __shared__ float zs[16][PT_];
  __shared__ float w3s[C_][16];
  for (int i = tid; i < C_*16; i += 256) w3s[i >> 4][i & 15] = w3[i];
  for (int e = tid; e < 16*PT_; e += 256) {
    int f = e / PT_, pt = e - f * PT_;
    float v = y16[((size_t)b*16 + f) * PT_ + pt] * ac[f] + bcf[f];
    zs[f][pt] = (v > 0.f) ? v : (__expf(v) - 1.f);
  }
  __syncthreads();
  for (int e = tid; e < C_ * P_; e += 256) {
    int c = e / P_, p = e - (e / P_) * P_;
    float b3 = bc3[c];
    float4 o = make_float4(b3, b3, b3, b3);
#pragma unroll
    for (int f = 0; f < 16; ++f) {
      float wv = w3s[c][f];
      float4 z = *(const float4*)&zs[f][p*4];
      o.x += wv * z.x; o.y += wv * z.y; o.z += wv * z.z; o.w += wv * z.w;
    }
    size_t idx = (((size_t)b * C_ + c) * P_ + p) * T_;
    float4 xr = *(const float4*)(pre1 + idx);
    float a1c = a1[c], b1c = b1[c];
    o.x += xr.x * a1c + b1c;
    o.y += xr.y * a1c + b1c;
    o.z += xr.z * a1c + b1c;
    o.w += xr.w * a1c + b1c;
    *(float4*)(pre2 + idx) = o;
  }
}

// K8: apply BN2 -> out
__global__ __launch_bounds__(256) void bnapply_kernel(
    const float* __restrict__ pre2, const float* __restrict__ a, const float* __restrict__ bs,
    float* __restrict__ out) {
  int i = blockIdx.x * 256 + threadIdx.x;
  if (i < (B_*C_*PT_)/4) {
    int row = (i * 4) / PT_;
    int c = row % C_;
    float4 v = *(const float4*)(pre2 + (size_t)i * 4);
    float ai = a[c], bi = bs[c];
    float4 o = make_float4(v.x*ai+bi, v.y*ai+bi, v.z*ai+bi, v.w*ai+bi);
    *(float4*)(out + (size_t)i * 4) = o;
  }
}

extern "C" void kernel_launch(void* const* d_in, const int* in_sizes, int n_in,
                              void* d_out, int out_size, void* d_ws, size_t ws_size,
                              hipStream_t stream) {
  const float* x        = (const float*)d_in[0];
  const float* w_qkv    = (const float*)d_in[1];
  const float* b_qkv    = (const float*)d_in[2];
  const float* rel      = (const float*)d_in[3];
  const float* g1       = (const float*)d_in[4];
  const float* beta1    = (const float*)d_in[5];
  const float* w_c1     = (const float*)d_in[6];
  const float* bc1      = (const float*)d_in[7];
  const float* w_c2     = (const float*)d_in[8];
  const float* bc2      = (const float*)d_in[9];
  const float* g_cfe    = (const float*)d_in[10];
  const float* beta_cfe = (const float*)d_in[11];
  const float* w_c3     = (const float*)d_in[12];
  const float* bc3      = (const float*)d_in[13];
  const float* g2       = (const float*)d_in[14];
  const float* beta2    = (const float*)d_in[15];
  float* out = (float*)d_out;
  char* ws = (char*)d_ws;

  // ws layout (bytes):
  //   0          q_ws bf16 (25,395,200)   [pre2 f32 aliases q+k after attn]
  //   25395200   k_ws bf16
  //   50790400   v_ws bf16
  //   76185600   pre1 f32 (50,790,400)    [xT bf16 27,262,976 + wbf 393,216 alias here pre-attn]
  //   126976000  y16  f32 (3,276,800)
  //   130252800  relp bf16 padded [112][128] (28,672)
  //   130281472  stats f32
  unsigned short* q_ws  = (unsigned short*)(ws);
  unsigned short* k_ws  = (unsigned short*)(ws + 25395200);
  unsigned short* v_ws  = (unsigned short*)(ws + 50790400);
  float* pre1           = (float*)(ws + 76185600);
  unsigned short* xT    = (unsigned short*)(ws + 76185600);   // alias (dead before attn writes pre1)
  unsigned short* wbf   = (unsigned short*)(ws + 76185600 + 27262976);
  float* y16            = (float*)(ws + 126976000);
  unsigned short* relp  = (unsigned short*)(ws + 130252800);
  float* st             = (float*)(ws + 130281472);
  float* a1 = st, *b1 = st + 256, *acf = st + 512, *bcf = st + 544, *a2 = st + 576, *b2 = st + 832;
  float* pre2           = (float*)ws;

  relcvt_kernel<<<56, 256, 0, stream>>>(rel, relp);
  wcvt_kernel<<<192, 256, 0, stream>>>(w_qkv, wbf);
  xt_kernel<<<dim3(16, 256), 256, 0, stream>>>(x, xT);
  qkv_mfma_kernel<<<dim3(6, 256), 256, 0, stream>>>(xT, wbf, b_qkv, q_ws, k_ws, v_ws);
  attn_kernel<<<2048, 256, 0, stream>>>(q_ws, k_ws, v_ws, relp, x, pre1);
  bnstat_kernel<<<248, 256, 0, stream>>>(pre1, g1, beta1, a1, b1, C_);
  cfe12_kernel<<<256, 256, 0, stream>>>(pre1, a1, b1, w_c1, bc1, w_c2, bc2, y16);
  bnstat_kernel<<<16, 256, 0, stream>>>(y16, g_cfe, beta_cfe, acf, bcf, 16);
  cfe3_kernel<<<256, 256, 0, stream>>>(y16, acf, bcf, w_c3, bc3, pre1, a1, b1, pre2);
  bnstat_kernel<<<248, 256, 0, stream>>>(pre2, g2, beta2, a2, b2, C_);
  bnapply_kernel<<<12400, 256, 0, stream>>>(pre2, a2, b2, out);
}

// Round 6
// 433.678 us; speedup vs baseline: 1.9994x; 1.1677x over previous
//
#include <hip/hip_runtime.h>

#define B_ 256
#define C_ 248
#define P_ 50
#define T_ 4
#define H_ 8
#define D_ 31
#define DH_ 124
#define PT_ 200
#define O3_ 744

typedef __attribute__((ext_vector_type(8))) short short8v;
typedef __attribute__((ext_vector_type(4))) float f32x4;

__device__ __forceinline__ float bf2f(unsigned short u) {
  union { unsigned int i; float f; } v; v.i = ((unsigned int)u) << 16; return v.f;
}
__device__ __forceinline__ unsigned short f2bf(float f) {
  union { float f; unsigned int i; } v; v.f = f;
  unsigned int r = v.i + 0x7fffu + ((v.i >> 16) & 1u);
  return (unsigned short)(r >> 16);
}

// K0: rel_emb fp32 -> bf16, zero-padded to [112][128]
__global__ void relcvt_kernel(const float* __restrict__ rel, unsigned short* __restrict__ out) {
  int i = blockIdx.x * 256 + threadIdx.x;
  if (i < 112 * 128) {
    int r = i >> 7, k = i & 127;
    out[i] = (r < 99 && k < DH_) ? f2bf(rel[r * DH_ + k]) : (unsigned short)0;
  }
}

// K0b: w_qkv fp32 [744][248] -> bf16 zero-padded [768][256]
__global__ void wcvt_kernel(const float* __restrict__ w, unsigned short* __restrict__ wbf) {
  int i = blockIdx.x * 256 + threadIdx.x;  // 768*64 ushort4 slots
  if (i < 768 * 64) {
    int o = i >> 6, c = (i & 63) * 4;
    ushort4 val = make_ushort4(0, 0, 0, 0);
    if (o < O3_ && c < C_) {
      float4 wv = *(const float4*)(w + (size_t)o * C_ + c);
      val.x = f2bf(wv.x); val.y = f2bf(wv.y); val.z = f2bf(wv.z); val.w = f2bf(wv.w);
    }
    *(ushort4*)(wbf + (size_t)o * 256 + c) = val;
  }
}

// K0c: x fp32 [b][248][200] -> xT bf16 [b][208][256] (pt-major, zero-padded)
__global__ __launch_bounds__(256) void xt_kernel(const float* __restrict__ x,
                                                 unsigned short* __restrict__ xT) {
  __shared__ float xs[64 * 65];
  const int tid = threadIdx.x;
  const int pt0 = (blockIdx.x & 3) * 64;
  const int c0 = (blockIdx.x >> 2) * 64;
  const int b = blockIdx.y;
#pragma unroll
  for (int pass = 0; pass < 4; ++pass) {
    int row = pass * 16 + (tid >> 4);       // c local
    int ptl4 = (tid & 15) * 4;              // pt local
    int c = c0 + row, pt = pt0 + ptl4;
    float4 v = make_float4(0.f, 0.f, 0.f, 0.f);
    if (c < C_) {
      const float* src = x + ((size_t)b * C_ + c) * PT_ + pt;
      if (pt + 3 < PT_) v = *(const float4*)src;
      else {
        if (pt + 0 < PT_) v.x = src[0];
        if (pt + 1 < PT_) v.y = src[1];
        if (pt + 2 < PT_) v.z = src[2];
        if (pt + 3 < PT_) v.w = src[3];
      }
    }
    xs[row * 65 + ptl4 + 0] = v.x; xs[row * 65 + ptl4 + 1] = v.y;
    xs[row * 65 + ptl4 + 2] = v.z; xs[row * 65 + ptl4 + 3] = v.w;
  }
  __syncthreads();
#pragma unroll
  for (int pass = 0; pass < 4; ++pass) {
    int ptl = pass * 16 + (tid >> 4);
    int cl4 = (tid & 15) * 4;
    int pt = pt0 + ptl;
    if (pt < 208) {
      ushort4 pk;
      pk.x = f2bf(xs[(cl4 + 0) * 65 + ptl]);
      pk.y = f2bf(xs[(cl4 + 1) * 65 + ptl]);
      pk.z = f2bf(xs[(cl4 + 2) * 65 + ptl]);
      pk.w = f2bf(xs[(cl4 + 3) * 65 + ptl]);
      *(ushort4*)(xT + ((size_t)b * 208 + pt) * 256 + c0 + cl4) = pk;
    }
  }
}

// K1: MFMA qkv GEMM. Per block: b, 128-o tile. M=pt (13x16 from xT), N=o (2x16/wave), K=256.
__global__ __launch_bounds__(256) void qkv_mfma_kernel(
    const unsigned short* __restrict__ xT, const unsigned short* __restrict__ wbf,
    const float* __restrict__ bias,
    unsigned short* __restrict__ q_ws, unsigned short* __restrict__ k_ws,
    unsigned short* __restrict__ v_ws) {
  const int tid = threadIdx.x;
  const int w = tid >> 6, l = tid & 63;
  const int lr = l & 15, lk = (l >> 4) * 8;
  const int b = blockIdx.y;
  const int o_w = blockIdx.x * 128 + w * 32;
  const unsigned short* xb = xT + (size_t)b * 208 * 256;

  const f32x4 zf = {0.f, 0.f, 0.f, 0.f};
  f32x4 acc0[13], acc1[13];
#pragma unroll
  for (int m = 0; m < 13; ++m) { acc0[m] = zf; acc1[m] = zf; }

#pragma unroll
  for (int ks = 0; ks < 8; ++ks) {
    int k0 = ks * 32 + lk;
    short8v b0 = *(const short8v*)(wbf + (size_t)(o_w + lr) * 256 + k0);
    short8v b1 = *(const short8v*)(wbf + (size_t)(o_w + 16 + lr) * 256 + k0);
#pragma unroll
    for (int m = 0; m < 13; ++m) {
      short8v a = *(const short8v*)(xb + (size_t)(m * 16 + lr) * 256 + k0);
      acc0[m] = __builtin_amdgcn_mfma_f32_16x16x32_bf16(a, b0, acc0[m], 0, 0, 0);
      acc1[m] = __builtin_amdgcn_mfma_f32_16x16x32_bf16(a, b1, acc1[m], 0, 0, 0);
    }
  }
#pragma unroll
  for (int n = 0; n < 2; ++n) {
    int o = o_w + n * 16 + lr;
    if (o < O3_) {
      float bo = bias[o];
      int wi = o / C_;
      int rem = o - wi * C_;
      int h = rem / D_;
      int d = rem - h * D_;
      unsigned short* dst = (wi == 0) ? q_ws : (wi == 1) ? k_ws : v_ws;
      size_t rowb = ((size_t)b * H_ + h) * P_;
#pragma unroll
      for (int m = 0; m < 13; ++m) {
        int p = 4 * m + (l >> 4);
        if (p < P_) {
          f32x4 av = (n == 0) ? acc0[m] : acc1[m];
          ushort4 pk;
          pk.x = f2bf(av[0] + bo); pk.y = f2bf(av[1] + bo);
          pk.z = f2bf(av[2] + bo); pk.w = f2bf(av[3] + bo);
          *(ushort4*)(dst + (rowb + p) * DH_ + d * T_) = pk;
        }
      }
    }
  }
}

// K2: per-(b,h) MFMA attention: (QK^T + rel bias) softmax PV + residual -> pre1
__global__ __launch_bounds__(256) void attn_kernel(
    const unsigned short* __restrict__ q_ws, const unsigned short* __restrict__ k_ws,
    const unsigned short* __restrict__ v_ws, const unsigned short* __restrict__ relp,
    const float* __restrict__ x, float* __restrict__ pre1) {
  __shared__ __align__(16) unsigned short Qs[64 * 128];
  __shared__ __align__(16) unsigned short Ks[64 * 128];
  __shared__ __align__(16) unsigned short Vt[128 * 64];
  __shared__ __align__(16) unsigned short Ps[64 * 64];
  __shared__ __align__(16) unsigned short brs[64 * 112];
  const int tid = threadIdx.x;
  const int bh = blockIdx.x, b = bh >> 3, h = bh & 7;
  const size_t off = (size_t)bh * (P_ * DH_);

  {
    float4 z = make_float4(0.f, 0.f, 0.f, 0.f);
    float4* z1 = (float4*)Qs; float4* z2 = (float4*)Ks; float4* z3 = (float4*)Vt;
    for (int i = tid; i < 1024; i += 256) { z1[i] = z; z2[i] = z; z3[i] = z; }
  }
  __syncthreads();
  const float scale = 0.17960530202677491f;
  for (int i = tid; i < 1550; i += 256) {
    int p = i / 31, kq = (i - p * 31) * 4;
    ushort4 qv = *(const ushort4*)(q_ws + off + p * DH_ + kq);
    qv.x = f2bf(bf2f(qv.x) * scale); qv.y = f2bf(bf2f(qv.y) * scale);
    qv.z = f2bf(bf2f(qv.z) * scale); qv.w = f2bf(bf2f(qv.w) * scale);
    *(ushort4*)((char*)Qs + ((p * 256 + kq * 2) ^ ((p & 7) << 4))) = qv;
    ushort4 kv = *(const ushort4*)(k_ws + off + p * DH_ + kq);
    *(ushort4*)((char*)Ks + ((p * 256 + kq * 2) ^ ((p & 7) << 4))) = kv;
    ushort4 vv = *(const ushort4*)(v_ws + off + p * DH_ + kq);
    unsigned short ve[4] = {vv.x, vv.y, vv.z, vv.w};
#pragma unroll
    for (int e = 0; e < 4; ++e) {
      int dh = kq + e;
      *(unsigned short*)((char*)Vt + ((dh * 128 + p * 2) ^ ((dh & 7) << 4))) = ve[e];
    }
  }
  __syncthreads();

  const int w = tid >> 6, l = tid & 63;
  const int lr = l & 15;
  const int lk = (l >> 4) * 8;
  const int arow = 16 * w + lr;
  const int prow0 = 16 * w + (l >> 4) * 4;

  const f32x4 zf = {0.f, 0.f, 0.f, 0.f};
  f32x4 accS[4]; f32x4 accR[7];
#pragma unroll
  for (int n = 0; n < 4; ++n) accS[n] = zf;
#pragma unroll
  for (int n = 0; n < 7; ++n) accR[n] = zf;

#pragma unroll
  for (int ks = 0; ks < 4; ++ks) {
    int k0 = ks * 32 + lk;
    short8v a = *(const short8v*)((const char*)Qs + ((arow * 256 + 2 * k0) ^ ((arow & 7) << 4)));
#pragma unroll
    for (int n = 0; n < 4; ++n) {
      int brow = 16 * n + lr;
      short8v bb = *(const short8v*)((const char*)Ks + ((brow * 256 + 2 * k0) ^ ((brow & 7) << 4)));
      accS[n] = __builtin_amdgcn_mfma_f32_16x16x32_bf16(a, bb, accS[n], 0, 0, 0);
    }
#pragma unroll
    for (int n = 0; n < 7; ++n) {
      int rrow = 16 * n + lr;
      short8v bb = *(const short8v*)(relp + rrow * 128 + k0);
      accR[n] = __builtin_amdgcn_mfma_f32_16x16x32_bf16(a, bb, accR[n], 0, 0, 0);
    }
  }
#pragma unroll
  for (int n = 0; n < 7; ++n)
#pragma unroll
    for (int r = 0; r < 4; ++r)
      brs[(prow0 + r) * 112 + 16 * n + lr] = f2bf(accR[n][r]);
  __syncthreads();

  float sv[4][4];
#pragma unroll
  for (int n = 0; n < 4; ++n)
#pragma unroll
    for (int r = 0; r < 4; ++r) {
      int p = prow0 + r, j = 16 * n + lr;
      if (p < P_ && j < P_)
        sv[n][r] = accS[n][r] + bf2f(brs[p * 112 + (49 + j - p)]);
      else
        sv[n][r] = -1e30f;
    }
#pragma unroll
  for (int r = 0; r < 4; ++r) {
    float mm = fmaxf(fmaxf(sv[0][r], sv[1][r]), fmaxf(sv[2][r], sv[3][r]));
    mm = fmaxf(mm, __shfl_xor(mm, 1));
    mm = fmaxf(mm, __shfl_xor(mm, 2));
    mm = fmaxf(mm, __shfl_xor(mm, 4));
    mm = fmaxf(mm, __shfl_xor(mm, 8));
    float ss = 0.f;
#pragma unroll
    for (int n = 0; n < 4; ++n) { float e = __expf(sv[n][r] - mm); sv[n][r] = e; ss += e; }
    ss += __shfl_xor(ss, 1); ss += __shfl_xor(ss, 2);
    ss += __shfl_xor(ss, 4); ss += __shfl_xor(ss, 8);
    float inv = 1.f / ss;
#pragma unroll
    for (int n = 0; n < 4; ++n) sv[n][r] *= inv;
  }
#pragma unroll
  for (int n = 0; n < 4; ++n)
#pragma unroll
    for (int r = 0; r < 4; ++r) {
      int p = prow0 + r, j = 16 * n + lr;
      *(unsigned short*)((char*)Ps + ((p * 128 + 2 * j) ^ ((p & 7) << 4))) = f2bf(sv[n][r]);
    }
  __syncthreads();

  f32x4 accO[8];
#pragma unroll
  for (int n = 0; n < 8; ++n) accO[n] = zf;
#pragma unroll
  for (int ks = 0; ks < 2; ++ks) {
    int j0 = ks * 32 + lk;
    short8v a = *(const short8v*)((const char*)Ps + ((arow * 128 + 2 * j0) ^ ((arow & 7) << 4)));
#pragma unroll
    for (int n = 0; n < 8; ++n) {
      int vrow = 16 * n + lr;
      short8v bb = *(const short8v*)((const char*)Vt + ((vrow * 128 + 2 * j0) ^ ((vrow & 7) << 4)));
      accO[n] = __builtin_amdgcn_mfma_f32_16x16x32_bf16(a, bb, accO[n], 0, 0, 0);
    }
  }
#pragma unroll
  for (int n = 0; n < 8; ++n) {
    int dh = 16 * n + lr;
    if (dh < DH_) {
      int c = h * D_ + (dh >> 2), t = dh & 3;
#pragma unroll
      for (int r = 0; r < 4; ++r) {
        int p = prow0 + r;
        if (p < P_) {
          size_t idx = (((size_t)b * C_ + c) * P_ + p) * T_ + t;
          pre1[idx] = accO[n][r] + x[idx];
        }
      }
    }
  }
}

// BN batch-stat reduction: per channel over (B, PT). 256 threads = one b each.
__global__ __launch_bounds__(256) void bnstat_kernel(
    const float* __restrict__ t, const float* __restrict__ g, const float* __restrict__ be,
    float* __restrict__ a, float* __restrict__ bs, int nch) {
  const int c = blockIdx.x;
  const int tid = threadIdx.x;
  const float* base = t + ((size_t)tid * nch + c) * PT_;
  float s = 0.f, s2 = 0.f;
  for (int i = 0; i < PT_; i += 4) {
    float4 v = *(const float4*)(base + i);
    s += v.x + v.y + v.z + v.w;
    s2 += v.x*v.x + v.y*v.y + v.z*v.z + v.w*v.w;
  }
#pragma unroll
  for (int off = 32; off > 0; off >>= 1) {
    s += __shfl_down(s, off);
    s2 += __shfl_down(s2, off);
  }
  __shared__ float r1[4], r2[4];
  if ((tid & 63) == 0) { r1[tid>>6] = s; r2[tid>>6] = s2; }
  __syncthreads();
  if (tid == 0) {
    s = r1[0]+r1[1]+r1[2]+r1[3];
    s2 = r2[0]+r2[1]+r2[2]+r2[3];
    const float inv = 1.f / (float)(B_ * PT_);
    float m = s * inv;
    float var = s2 * inv - m * m;
    float ai = g[c] * rsqrtf(var + 1e-5f);
    a[c] = ai;
    bs[c] = be[c] - m * ai;
  }
}

// K4a: pre1 f32 [b][248][200] -> p1T bf16 [b*50+p][1024] (K = c*4+t', col992=1.0, rest 0)
__global__ __launch_bounds__(256) void p1t_kernel(const float* __restrict__ pre1,
                                                  unsigned short* __restrict__ p1T) {
  __shared__ float xs[64][205];
  const int b = blockIdx.x;
  const int tid = threadIdx.x;
  for (int c0 = 0; c0 < C_; c0 += 64) {
    int R = (C_ - c0 < 64) ? (C_ - c0) : 64;
    __syncthreads();
    for (int e = tid; e < R * 50; e += 256) {
      int row = e / 50, pq = e - (e / 50) * 50;
      float4 v = *(const float4*)(pre1 + ((size_t)b * C_ + c0 + row) * PT_ + pq * 4);
      xs[row][pq*4+0]=v.x; xs[row][pq*4+1]=v.y; xs[row][pq*4+2]=v.z; xs[row][pq*4+3]=v.w;
    }
    __syncthreads();
    for (int u = tid; u < 50 * R; u += 256) {
      int p = u / R, cl = u - (u / R) * R;
      ushort4 pk;
      pk.x = f2bf(xs[cl][p*4+0]); pk.y = f2bf(xs[cl][p*4+1]);
      pk.z = f2bf(xs[cl][p*4+2]); pk.w = f2bf(xs[cl][p*4+3]);
      *(ushort4*)(p1T + ((size_t)b*50 + p) * 1024 + (c0+cl)*4) = pk;
    }
  }
  for (int u = tid; u < 50 * 8; u += 256) {
    int p = u >> 3, g = u & 7;
    ushort4 val = make_ushort4(0,0,0,0);
    if (g == 0) val.x = 0x3F80;  // 1.0 bf16 const column
    *(ushort4*)(p1T + ((size_t)b*50 + p) * 1024 + 992 + g*4) = val;
  }
}

// K4b: build Wbig bf16 [64 n=(f,t)][1024 K=(c,t')+const] folding conv taps, a1, b1, bc
__global__ __launch_bounds__(256) void wcfe_kernel(
    const float* __restrict__ w1, const float* __restrict__ bc1,
    const float* __restrict__ w2, const float* __restrict__ bc2,
    const float* __restrict__ a1, const float* __restrict__ b1,
    unsigned short* __restrict__ Wbig) {
  const int n = blockIdx.x;       // 0..63
  const int f = n >> 2, t = n & 3;
  const int tid = threadIdx.x;
  __shared__ float red[256];
  float partial = 0.f;
  if (tid < C_) {
    int c = tid;
    float tv[4];
    float tsum = 0.f;
#pragma unroll
    for (int tp = 0; tp < 4; ++tp) {
      int dt = tp - t;
      float v = 0.f;
      if (f < 8) { if (dt >= -1 && dt <= 1) v = w1[(f * C_ + c) * 3 + dt + 1]; }
      else       { if (dt >= -2 && dt <= 2) v = w2[((f - 8) * C_ + c) * 5 + dt + 2]; }
      tv[tp] = v; tsum += v;
    }
    float ac = a1[c];
#pragma unroll
    for (int tp = 0; tp < 4; ++tp)
      Wbig[n * 1024 + c * 4 + tp] = f2bf(ac * tv[tp]);
    partial = b1[c] * tsum;
  } else {
#pragma unroll
    for (int tp = 0; tp < 4; ++tp) {
      int col = tid * 4 + tp;
      if (col > 992 && col < 1024) Wbig[n * 1024 + col] = 0;
    }
  }
  red[tid] = partial;
  __syncthreads();
  for (int s = 128; s > 0; s >>= 1) {
    if (tid < s) red[tid] += red[tid + s];
    __syncthreads();
  }
  if (tid == 0) {
    float bias = (f < 8) ? bc1[f] : bc2[f - 8];
    Wbig[n * 1024 + 992] = f2bf(bias + red[0]);
  }
}

// K4c: MFMA GEMM: y16[m=(b,p), n=(f,t)] = p1T[m] . Wbig[n].  M=12800, N=64, K=1024.
__global__ __launch_bounds__(256) void cfe12g_kernel(
    const unsigned short* __restrict__ p1T, const unsigned short* __restrict__ Wbig,
    float* __restrict__ y16) {
  const int tid = threadIdx.x;
  const int w = tid >> 6, l = tid & 63;
  const int lr = l & 15, lk = (l >> 4) * 8;
  const int m0 = blockIdx.x * 32;
  const f32x4 zf = {0.f, 0.f, 0.f, 0.f};
  f32x4 acc0 = zf, acc1 = zf;
  const unsigned short* wrow = Wbig + (size_t)(w * 16 + lr) * 1024;
#pragma unroll
  for (int ks = 0; ks < 32; ++ks) {
    int k0 = ks * 32 + lk;
    short8v bfr = *(const short8v*)(wrow + k0);
    short8v a0 = *(const short8v*)(p1T + (size_t)(m0 + lr) * 1024 + k0);
    short8v a1v = *(const short8v*)(p1T + (size_t)(m0 + 16 + lr) * 1024 + k0);
    acc0 = __builtin_amdgcn_mfma_f32_16x16x32_bf16(a0, bfr, acc0, 0, 0, 0);
    acc1 = __builtin_amdgcn_mfma_f32_16x16x32_bf16(a1v, bfr, acc1, 0, 0, 0);
  }
  const int n = w * 16 + lr, f = n >> 2, tt = n & 3;
#pragma unroll
  for (int mt = 0; mt < 2; ++mt) {
    f32x4 av = (mt == 0) ? acc0 : acc1;
#pragma unroll
    for (int r = 0; r < 4; ++r) {
      int m = m0 + mt * 16 + (l >> 4) * 4 + r;
      int b = m / 50, p = m - (m / 50) * 50;
      y16[((size_t)b * 16 + f) * PT_ + p * 4 + tt] = av[r];
    }
  }
}

// K6: ELU(BN_cfe(y16)) -> conv3 (16->248) + BN1-residual -> pre2
__global__ __launch_bounds__(256) void cfe3_kernel(
    const float* __restrict__ y16, const float* __restrict__ ac, const float* __restrict__ bcf,
    const float* __restrict__ w3, const float* __restrict__ bc3,
    const float* __restrict__ pre1, const float* __restrict__ a1, const float* __restrict__ b1,
    float* __restrict__ pre2) {
  const int b = blockIdx.x;
  const int tid = threadIdx.x;
  __shared__ float zs[16][PT_];
  __shared__ float w3s[C_][16];
  for (int i = tid; i < C_*16; i += 256) w3s[i >> 4][i & 15] = w3[i];
  for (int e = tid; e < 16*PT_; e += 256) {
    int f = e / PT_, pt = e - f * PT_;
    float v = y16[((size_t)b*16 + f) * PT_ + pt] * ac[f] + bcf[f];
    zs[f][pt] = (v > 0.f) ? v : (__expf(v) - 1.f);
  }
  __syncthreads();
  for (int e = tid; e < C_ * P_; e += 256) {
    int c = e / P_, p = e - (e / P_) * P_;
    float b3 = bc3[c];
    float4 o = make_float4(b3, b3, b3, b3);
#pragma unroll
    for (int f = 0; f < 16; ++f) {
      float wv = w3s[c][f];
      float4 z = *(const float4*)&zs[f][p*4];
      o.x += wv * z.x; o.y += wv * z.y; o.z += wv * z.z; o.w += wv * z.w;
    }
    size_t idx = (((size_t)b * C_ + c) * P_ + p) * T_;
    float4 xr = *(const float4*)(pre1 + idx);
    float a1c = a1[c], b1c = b1[c];
    o.x += xr.x * a1c + b1c;
    o.y += xr.y * a1c + b1c;
    o.z += xr.z * a1c + b1c;
    o.w += xr.w * a1c + b1c;
    *(float4*)(pre2 + idx) = o;
  }
}

// K8: apply BN2 -> out
__global__ __launch_bounds__(256) void bnapply_kernel(
    const float* __restrict__ pre2, const float* __restrict__ a, const float* __restrict__ bs,
    float* __restrict__ out) {
  int i = blockIdx.x * 256 + threadIdx.x;
  if (i < (B_*C_*PT_)/4) {
    int row = (i * 4) / PT_;
    int c = row % C_;
    float4 v = *(const float4*)(pre2 + (size_t)i * 4);
    float ai = a[c], bi = bs[c];
    float4 o = make_float4(v.x*ai+bi, v.y*ai+bi, v.z*ai+bi, v.w*ai+bi);
    *(float4*)(out + (size_t)i * 4) = o;
  }
}

extern "C" void kernel_launch(void* const* d_in, const int* in_sizes, int n_in,
                              void* d_out, int out_size, void* d_ws, size_t ws_size,
                              hipStream_t stream) {
  const float* x        = (const float*)d_in[0];
  const float* w_qkv    = (const float*)d_in[1];
  const float* b_qkv    = (const float*)d_in[2];
  const float* rel      = (const float*)d_in[3];
  const float* g1       = (const float*)d_in[4];
  const float* beta1    = (const float*)d_in[5];
  const float* w_c1     = (const float*)d_in[6];
  const float* bc1      = (const float*)d_in[7];
  const float* w_c2     = (const float*)d_in[8];
  const float* bc2      = (const float*)d_in[9];
  const float* g_cfe    = (const float*)d_in[10];
  const float* beta_cfe = (const float*)d_in[11];
  const float* w_c3     = (const float*)d_in[12];
  const float* bc3      = (const float*)d_in[13];
  const float* g2       = (const float*)d_in[14];
  const float* beta2    = (const float*)d_in[15];
  float* out = (float*)d_out;
  char* ws = (char*)d_ws;

  // ws layout (bytes):
  //   0          q_ws bf16 (25,395,200)   [p1T bf16 26,214,400 aliases q+k after attn;
  //                                        pre2 f32 aliases after cfe12g]
  //   25395200   k_ws bf16
  //   50790400   v_ws bf16
  //   76185600   pre1 f32 (50,790,400)    [xT bf16 + wbf alias here pre-attn]
  //   126976000  y16  f32 (3,276,800)
  //   130252800  relp bf16 [112][128] (28,672)
  //   130281472  Wbig bf16 [64][1024] (131,072)
  //   130412544  stats f32
  unsigned short* q_ws  = (unsigned short*)(ws);
  unsigned short* k_ws  = (unsigned short*)(ws + 25395200);
  unsigned short* v_ws  = (unsigned short*)(ws + 50790400);
  float* pre1           = (float*)(ws + 76185600);
  unsigned short* xT    = (unsigned short*)(ws + 76185600);
  unsigned short* wbf   = (unsigned short*)(ws + 76185600 + 27262976);
  float* y16            = (float*)(ws + 126976000);
  unsigned short* relp  = (unsigned short*)(ws + 130252800);
  unsigned short* Wbig  = (unsigned short*)(ws + 130281472);
  float* st             = (float*)(ws + 130412544);
  float* a1 = st, *b1 = st + 256, *acf = st + 512, *bcf = st + 544, *a2 = st + 576, *b2 = st + 832;
  unsigned short* p1T   = (unsigned short*)ws;   // alias q+k region (dead after attn)
  float* pre2           = (float*)ws;            // alias (written by cfe3, after p1T dead)

  relcvt_kernel<<<56, 256, 0, stream>>>(rel, relp);
  wcvt_kernel<<<192, 256, 0, stream>>>(w_qkv, wbf);
  xt_kernel<<<dim3(16, 256), 256, 0, stream>>>(x, xT);
  qkv_mfma_kernel<<<dim3(6, 256), 256, 0, stream>>>(xT, wbf, b_qkv, q_ws, k_ws, v_ws);
  attn_kernel<<<2048, 256, 0, stream>>>(q_ws, k_ws, v_ws, relp, x, pre1);
  bnstat_kernel<<<248, 256, 0, stream>>>(pre1, g1, beta1, a1, b1, C_);
  p1t_kernel<<<256, 256, 0, stream>>>(pre1, p1T);
  wcfe_kernel<<<64, 256, 0, stream>>>(w_c1, bc1, w_c2, bc2, a1, b1, Wbig);
  cfe12g_kernel<<<400, 256, 0, stream>>>(p1T, Wbig, y16);
  bnstat_kernel<<<16, 256, 0, stream>>>(y16, g_cfe, beta_cfe, acf, bcf, 16);
  cfe3_kernel<<<256, 256, 0, stream>>>(y16, acf, bcf, w_c3, bc3, pre1, a1, b1, pre2);
  bnstat_kernel<<<248, 256, 0, stream>>>(pre2, g2, beta2, a2, b2, C_);
  bnapply_kernel<<<12400, 256, 0, stream>>>(pre2, a2, b2, out);
}